// Round 1
// 2103.410 us; speedup vs baseline: 1.6618x; 1.6618x over previous
//
#include <hip/hip_runtime.h>
#include <hip/hip_bf16.h>
#include <math.h>

// ---------------------------------------------------------------------------
// MultiScaleWindowGridTransformer: B=8, C=256, H=W=128, WS=8, NH=8, HD=32
// Round 5: weights pre-converted to bf16 (single GEMM/LN launches),
// GEMM staging via global_load_lds width=16 (m97 pattern, linear LDS),
// bijective XCD swizzle on GEMM grids, parallel softmax in attn,
// NaN-sentinel scan kernels removed (diagnostics only, ~300us of traffic).
// ---------------------------------------------------------------------------

#define CC 256
#define HH 128
#define WW 128
#define HWSZ 16384

typedef __attribute__((ext_vector_type(8))) short short8v;   // 8 bf16 (4 VGPRs)
typedef __attribute__((ext_vector_type(4))) float float4v;   // MFMA C/D frag

#if defined(__has_builtin)
#if __has_builtin(__builtin_amdgcn_global_load_lds)
#define USE_GLDS 1
#endif
#endif
#ifndef USE_GLDS
#define USE_GLDS 0
#endif

static __device__ __forceinline__ float bf2f(unsigned short u) {
    union { float f; unsigned int i; } x; x.i = ((unsigned int)u) << 16; return x.f;
}
static __device__ __forceinline__ unsigned short f2bf(float f) {
    union { float f; unsigned int i; } x; x.f = f;
    unsigned int r = x.i + 0x7FFFu + ((x.i >> 16) & 1u);   // RNE
    return (unsigned short)(r >> 16);
}
template<int FMT> static __device__ __forceinline__ float ldin(const void* p, size_t i) {
    if (FMT == 0) return bf2f(((const unsigned short*)p)[i]);
    return ((const float*)p)[i];
}

#if USE_GLDS
static __device__ __forceinline__ void gload16(const unsigned short* g, unsigned short* l) {
    // HW semantics (guide m104): LDS dest = wave-uniform base + lane*16B; global src per-lane.
    __builtin_amdgcn_global_load_lds(
        (const __attribute__((address_space(1))) unsigned int*)g,
        (__attribute__((address_space(3))) unsigned int*)l, 16, 0, 0);
}
#endif

// --------------------------- format probe ----------------------------------
__global__ void probe_kernel(const unsigned short* x, int* flags) {
    __shared__ int mx[256];
    int m = 0;
    for (int i = threadIdx.x; i < 65536; i += 256) {
        int e = (x[i] >> 7) & 0xFF;
        m = m > e ? m : e;
    }
    mx[threadIdx.x] = m; __syncthreads();
    for (int s = 128; s > 0; s >>= 1) {
        if (threadIdx.x < s) mx[threadIdx.x] = mx[threadIdx.x] > mx[threadIdx.x + s] ? mx[threadIdx.x] : mx[threadIdx.x + s];
        __syncthreads();
    }
    if (threadIdx.x == 0) flags[0] = (mx[0] > 200) ? 1 : 0;
}
__global__ void report_ws_kernel(unsigned short* out, long long n, float code) {
    long long i = (long long)blockIdx.x * blockDim.x + threadIdx.x;
    const long long st = (long long)gridDim.x * blockDim.x;
    unsigned short c = f2bf(code);
    for (; i < n; i += st) out[i] = c;
}

// --------------------------- weight normalization --------------------------
// Concatenated bf16 weight arena offsets (elements)
#define WF_OFF   0
#define WQW_OFF  196608
#define WOW_OFF  393216
#define WQG_OFF  458752
#define WOG_OFF  655360
#define M1W_OFF  720896
#define M2W_OFF  983040
#define WTOT     1245184
// f32 bias/gain arena offsets (elements)
#define BF_OFF   0
#define GW_OFF   256
#define BW_OFF   512
#define BQW_OFF  768
#define BOW_OFF  1536
#define GG_OFF   1792
#define BG_OFF   2048
#define BQG_OFF  2304
#define BOG_OFF  3072
#define GM_OFF   3328
#define BM_OFF   3584
#define M1B_OFF  3840
#define M2B_OFF  4864
#define BTOT     5120

template<int FMT>
__global__ __launch_bounds__(256) void convert_weights_kernel(
    const void* __restrict__ wf, const void* __restrict__ wqkv_w, const void* __restrict__ wo_w,
    const void* __restrict__ wqkv_g, const void* __restrict__ wo_g,
    const void* __restrict__ m1w, const void* __restrict__ m2w,
    unsigned short* __restrict__ out, const int* __restrict__ flags)
{
    if (flags[0] != FMT) return;
    int i = blockIdx.x * 256 + threadIdx.x;
    const int st = gridDim.x * 256;
    for (; i < WTOT; i += st) {
        const void* src; int off;
        if (i < WQW_OFF)      { src = wf;     off = i; }
        else if (i < WOW_OFF) { src = wqkv_w; off = i - WQW_OFF; }
        else if (i < WQG_OFF) { src = wo_w;   off = i - WOW_OFF; }
        else if (i < WOG_OFF) { src = wqkv_g; off = i - WQG_OFF; }
        else if (i < M1W_OFF) { src = wo_g;   off = i - WOG_OFF; }
        else if (i < M2W_OFF) { src = m1w;    off = i - M1W_OFF; }
        else                  { src = m2w;    off = i - M2W_OFF; }
        out[i] = (FMT == 0) ? ((const unsigned short*)src)[off]
                            : f2bf(((const float*)src)[off]);
    }
}

template<int FMT>
__global__ __launch_bounds__(256) void convert_bias_kernel(
    const void* bf_, const void* gw, const void* bw, const void* bqkv_w, const void* bo_w,
    const void* gg, const void* bg, const void* bqkv_g, const void* bo_g,
    const void* gm, const void* bm, const void* m1b, const void* m2b,
    float* __restrict__ out, const int* __restrict__ flags)
{
    if (flags[0] != FMT) return;
    int i = blockIdx.x * 256 + threadIdx.x;
    if (i >= BTOT) return;
    const void* src; int off;
    if (i < GW_OFF)        { src = bf_;    off = i; }
    else if (i < BW_OFF)   { src = gw;     off = i - GW_OFF; }
    else if (i < BQW_OFF)  { src = bw;     off = i - BW_OFF; }
    else if (i < BOW_OFF)  { src = bqkv_w; off = i - BQW_OFF; }
    else if (i < GG_OFF)   { src = bo_w;   off = i - BOW_OFF; }
    else if (i < BG_OFF)   { src = gg;     off = i - GG_OFF; }
    else if (i < BQG_OFF)  { src = bg;     off = i - BG_OFF; }
    else if (i < BOG_OFF)  { src = bqkv_g; off = i - BQG_OFF; }
    else if (i < GM_OFF)   { src = bo_g;   off = i - BOG_OFF; }
    else if (i < BM_OFF)   { src = gm;     off = i - GM_OFF; }
    else if (i < M1B_OFF)  { src = bm;     off = i - BM_OFF; }
    else if (i < M2B_OFF)  { src = m1b;    off = i - M1B_OFF; }
    else                   { src = m2b;    off = i - M2B_OFF; }
    out[i] = ldin<FMT>(src, off);
}

// --------------------------- pipeline kernels ------------------------------
template<int FMT>
__global__ __launch_bounds__(256) void transpose_in_kernel(
    const void* __restrict__ in, float* __restrict__ out, const int* __restrict__ flags)
{
    if (flags[0] != FMT) return;
    __shared__ float tile[64][65];
    const int b  = blockIdx.z;
    const int s0 = blockIdx.x * 64;
    const int r0 = blockIdx.y * 64;
    const int tx = threadIdx.x & 63;
    const int ty = threadIdx.x >> 6;
    const size_t sb = (size_t)b * CC * HWSZ;
    float* dst = out + (size_t)b * HWSZ * CC;
#pragma unroll
    for (int rr = 0; rr < 16; ++rr) {
        int row = ty + rr * 4;
        tile[row][tx] = ldin<FMT>(in, sb + (size_t)(r0 + row) * HWSZ + s0 + tx);
    }
    __syncthreads();
#pragma unroll
    for (int rr = 0; rr < 16; ++rr) {
        int srow = ty + rr * 4;
        dst[(size_t)(s0 + srow) * CC + r0 + tx] = tile[tx][srow];
    }
}

template<int FMT>
__global__ __launch_bounds__(256) void transpose_out_kernel(
    const float* __restrict__ in, void* __restrict__ out, const int* __restrict__ flags)
{
    if (flags[0] != FMT) return;
    __shared__ float tile[64][65];
    const int b  = blockIdx.z;
    const int h0 = blockIdx.x * 64;
    const int c0 = blockIdx.y * 64;
    const int tx = threadIdx.x & 63;
    const int ty = threadIdx.x >> 6;
    const float* src = in + (size_t)b * HWSZ * CC;
    const size_t db = (size_t)b * CC * HWSZ;
#pragma unroll
    for (int rr = 0; rr < 16; ++rr) {
        int row = ty + rr * 4;
        tile[row][tx] = src[(size_t)(h0 + row) * CC + c0 + tx];
    }
    __syncthreads();
#pragma unroll
    for (int rr = 0; rr < 16; ++rr) {
        int crow = ty + rr * 4;
        size_t di = db + (size_t)(c0 + crow) * HWSZ + h0 + tx;
        float v = tile[tx][crow];
        if (FMT) ((float*)out)[di] = v;
        else ((unsigned short*)out)[di] = f2bf(v);
    }
}

template<int FMT>
__global__ __launch_bounds__(256) void dwconv_cat_kernel(
    const void* __restrict__ x,
    const void* __restrict__ w1, const void* __restrict__ b1,
    const void* __restrict__ w2, const void* __restrict__ b2,
    const void* __restrict__ w3, const void* __restrict__ b3,
    unsigned short* __restrict__ cat, int Mc, const int* __restrict__ flags)
{
    if (flags[0] != FMT) return;
    __shared__ float patch[8][136];
    __shared__ float wt[83];
    const int hb = blockIdx.x;
    const int c  = blockIdx.y;
    const int b  = blockIdx.z;
    const int tid = threadIdx.x;

    if (tid < 83) {
        float v;
        if (tid < 9)       v = ldin<FMT>(w1, c * 9 + tid);
        else if (tid < 34) v = ldin<FMT>(w2, c * 25 + (tid - 9));
        else               v = ldin<FMT>(w3, c * 49 + (tid - 34));
        wt[tid] = v;
    }
    const int h0 = hb * 2;
    const size_t xb = ((size_t)b * CC + c) * HWSZ;
    for (int i = tid; i < 8 * 136; i += 256) {
        int r = i / 136, col = i % 136;
        int gh = h0 - 3 + r, gw = col - 3;
        float v = 0.f;
        if (gh >= 0 && gh < HH && gw >= 0 && gw < WW) v = ldin<FMT>(x, xb + gh * WW + gw);
        patch[r][col] = v;
    }
    __syncthreads();

    const int w  = tid & 127;
    const int dh = tid >> 7;
    const int pr = dh + 3;
    float s1 = ldin<FMT>(b1, c), s2 = ldin<FMT>(b2, c), s3 = ldin<FMT>(b3, c);
#pragma unroll
    for (int dy = -1; dy <= 1; ++dy)
#pragma unroll
        for (int dx = -1; dx <= 1; ++dx)
            s1 += patch[pr + dy][w + 3 + dx] * wt[(dy + 1) * 3 + (dx + 1)];
#pragma unroll
    for (int dy = -2; dy <= 2; ++dy)
#pragma unroll
        for (int dx = -2; dx <= 2; ++dx)
            s2 += patch[pr + dy][w + 3 + dx] * wt[9 + (dy + 2) * 5 + (dx + 2)];
#pragma unroll
    for (int dy = -3; dy <= 3; ++dy)
#pragma unroll
        for (int dx = -3; dx <= 3; ++dx)
            s3 += patch[pr + dy][w + 3 + dx] * wt[34 + (dy + 3) * 7 + (dx + 3)];

    const size_t m = (size_t)b * HWSZ + (size_t)(h0 + dh) * WW + w;
    cat[(size_t)c * Mc + m]         = f2bf(s1);
    cat[(size_t)(256 + c) * Mc + m] = f2bf(s2);
    cat[(size_t)(512 + c) * Mc + m] = f2bf(s3);
}

// ---------------------------------------------------------------------------
// MFMA GEMM: C[M,N] = A*W^T + bias. W bf16 [N][K] row-major (pre-converted).
// ALAYOUT 0: A [M][K] bf16, staged via global_load_lds (linear [128][64] LDS,
//            m97 pattern; read conflicts accepted — T2 null at 128x128+2ph).
// ALAYOUT 1: A K-major [K][lda], VALU transpose staging, pad-72 LDS.
// EPI 0: bf16 store; 1: GELU->bf16; 2: += f32.
// Bijective XCD swizzle on block ids (nwg % 8 == 0 for all launches).
// ---------------------------------------------------------------------------
template<int ALAYOUT, int EPI>
__global__ __launch_bounds__(256) void gemm_mfma_kernel(
    const unsigned short* __restrict__ A, const unsigned short* __restrict__ Bw,
    const float* __restrict__ bias, void* __restrict__ Cout,
    int N, int K, int lda)
{
    constexpr int ASTR = ALAYOUT ? 72 : 64;
    __shared__ unsigned short As[128 * ASTR];
    __shared__ unsigned short Bs[128 * 64];
    const int tid  = threadIdx.x;
    const int lane = tid & 63;
    const int wv   = tid >> 6;
    const int wm   = (wv >> 1) * 64;
    const int wn   = (wv & 1) * 64;
    const int l15  = lane & 15;
    const int quad = lane >> 4;

    // XCD-aware swizzle: contiguous logical chunks per XCD (A-panel L2 reuse)
    const int nbx = gridDim.x;
    const int nwg = nbx * gridDim.y;
    const int bid = blockIdx.y * nbx + blockIdx.x;
    const int swz = (bid & 7) * (nwg >> 3) + (bid >> 3);
    const int m0 = (swz / nbx) * 128;
    const int n0 = (swz % nbx) * 128;

    const int sr   = lane >> 3;        // staging: 8 lanes per row
    const int scol = (lane & 7) * 8;   // 16B per lane

    float4v acc[4][4] = {};

    for (int k0 = 0; k0 < K; k0 += 64) {
        __syncthreads();
        // ---- stage A tile
        if (ALAYOUT == 0) {
            const unsigned short* ga = A + (size_t)(m0 + wv * 32 + sr) * K + k0 + scol;
#pragma unroll
            for (int p = 0; p < 4; ++p) {
                unsigned short* lb = &As[(wv * 32 + p * 8) * 64];
#if USE_GLDS
                gload16(ga + (size_t)(p * 8) * K, lb);
#else
                *(short8v*)(lb + lane * 8) = *(const short8v*)(ga + (size_t)(p * 8) * K);
#endif
            }
        } else {
#pragma unroll
            for (int p = 0; p < 4; ++p) {
                const int k  = p * 16 + (tid >> 4);
                const int mm = (tid & 15) * 8;
                const unsigned short* g = A + (size_t)(k0 + k) * lda + m0 + mm;
                ushort4 va = *(const ushort4*)g;
                ushort4 vb = *(const ushort4*)(g + 4);
                As[(mm + 0) * 72 + k] = va.x; As[(mm + 1) * 72 + k] = va.y;
                As[(mm + 2) * 72 + k] = va.z; As[(mm + 3) * 72 + k] = va.w;
                As[(mm + 4) * 72 + k] = vb.x; As[(mm + 5) * 72 + k] = vb.y;
                As[(mm + 6) * 72 + k] = vb.z; As[(mm + 7) * 72 + k] = vb.w;
            }
        }
        // ---- stage W tile (always bf16 [N][K])
        {
            const unsigned short* gb = Bw + (size_t)(n0 + wv * 32 + sr) * K + k0 + scol;
#pragma unroll
            for (int p = 0; p < 4; ++p) {
                unsigned short* lb = &Bs[(wv * 32 + p * 8) * 64];
#if USE_GLDS
                gload16(gb + (size_t)(p * 8) * K, lb);
#else
                *(short8v*)(lb + lane * 8) = *(const short8v*)(gb + (size_t)(p * 8) * K);
#endif
            }
        }
#if USE_GLDS
        asm volatile("s_waitcnt vmcnt(0)" ::: "memory");
#endif
        __syncthreads();

        // ---- 2 k-steps of 32, 16 MFMA each per wave
#pragma unroll
        for (int ks = 0; ks < 64; ks += 32) {
            short8v af[4], bfv[4];
#pragma unroll
            for (int i = 0; i < 4; ++i)
                af[i] = *(const short8v*)&As[(wm + i * 16 + l15) * ASTR + ks + quad * 8];
#pragma unroll
            for (int i = 0; i < 4; ++i)
                bfv[i] = *(const short8v*)&Bs[(wn + i * 16 + l15) * 64 + ks + quad * 8];
#pragma unroll
            for (int mi = 0; mi < 4; ++mi)
#pragma unroll
                for (int ni = 0; ni < 4; ++ni)
                    acc[mi][ni] = __builtin_amdgcn_mfma_f32_16x16x32_bf16(
                        af[mi], bfv[ni], acc[mi][ni], 0, 0, 0);
        }
    }

    // ---- epilogue
    float bv[4];
#pragma unroll
    for (int ni = 0; ni < 4; ++ni) bv[ni] = bias[n0 + wn + ni * 16 + l15];

#pragma unroll
    for (int mi = 0; mi < 4; ++mi) {
#pragma unroll
        for (int r = 0; r < 4; ++r) {
            const size_t row = (size_t)(m0 + wm + mi * 16 + quad * 4 + r);
#pragma unroll
            for (int ni = 0; ni < 4; ++ni) {
                const int col = n0 + wn + ni * 16 + l15;
                float v = acc[mi][ni][r] + bv[ni];
                if (EPI == 0) {
                    ((unsigned short*)Cout)[row * N + col] = f2bf(v);
                } else if (EPI == 1) {
                    float g = 0.5f * v * (1.0f + erff(v * 0.70710678118654752f));
                    ((unsigned short*)Cout)[row * N + col] = f2bf(g);
                } else {
                    ((float*)Cout)[row * N + col] += v;
                }
            }
        }
    }
}

// LayerNorm over C=256. FIN 0: bf16 input; FIN 1: f32 input. g/b f32 (converted).
template<int FIN>
__global__ __launch_bounds__(256) void ln_kernel(
    const void* __restrict__ inv, const float* __restrict__ g,
    const float* __restrict__ b, unsigned short* __restrict__ out)
{
    const int lane = threadIdx.x & 63;
    const int wv   = threadIdx.x >> 6;
    const size_t m = (size_t)blockIdx.x * 4 + wv;
    const int c0 = lane * 4;
    float v[4];
    if (FIN == 0) {
        ushort4 u = *(const ushort4*)((const unsigned short*)inv + m * CC + c0);
        v[0] = bf2f(u.x); v[1] = bf2f(u.y); v[2] = bf2f(u.z); v[3] = bf2f(u.w);
    } else {
        float4 f = *(const float4*)((const float*)inv + m * CC + c0);
        v[0] = f.x; v[1] = f.y; v[2] = f.z; v[3] = f.w;
    }
    float s  = v[0] + v[1] + v[2] + v[3];
    float sq = v[0]*v[0] + v[1]*v[1] + v[2]*v[2] + v[3]*v[3];
#pragma unroll
    for (int off = 32; off > 0; off >>= 1) {
        s  += __shfl_xor(s,  off);
        sq += __shfl_xor(sq, off);
    }
    const float mean = s * 0.00390625f;
    float var = sq * 0.00390625f - mean * mean;
    if (var < 0.f) var = 0.f;
    const float rs = rsqrtf(var + 1e-5f);
    ushort4 o;
    o.x = f2bf((v[0] - mean) * rs * g[c0 + 0] + b[c0 + 0]);
    o.y = f2bf((v[1] - mean) * rs * g[c0 + 1] + b[c0 + 1]);
    o.z = f2bf((v[2] - mean) * rs * g[c0 + 2] + b[c0 + 2]);
    o.w = f2bf((v[3] - mean) * rs * g[c0 + 3] + b[c0 + 3]);
    *(ushort4*)(out + m * CC + c0) = o;
}

// Windowed attention. MODE 0 window (reverse = inverse); MODE 1 grid:
// token (p,q) of window (i2,j2) scatters to h'=j2*8+(i2>>1), w'=(i2&1)*64+p*8+q.
template<int MODE>
__global__ __launch_bounds__(256) void attn_kernel(
    const unsigned short* __restrict__ qkv, unsigned short* __restrict__ attn_out)
{
    __shared__ float qs[64][36];
    __shared__ float ks[64][36];
    __shared__ float vs[64][36];
    __shared__ float S[64][68];
    const int tid = threadIdx.x;
    const int wi  = blockIdx.x;
    const int b   = wi >> 8;
    const int rem = wi & 255;
    const int i2  = rem >> 4;
    const int j2  = rem & 15;

    const int t  = tid >> 2;
    const int c8 = (tid & 3) * 8;
    const int p = t >> 3, qq = t & 7;
    int h_r, w_r, h_w, w_w;
    if (MODE == 0) {
        h_r = i2 * 8 + p;  w_r = j2 * 8 + qq;
        h_w = h_r;         w_w = w_r;
    } else {
        h_r = p * 16 + i2; w_r = qq * 16 + j2;
        h_w = j2 * 8 + (i2 >> 1);
        w_w = (i2 & 1) * 64 + p * 8 + qq;
    }
    const size_t gt_r = (size_t)b * HWSZ + (size_t)h_r * WW + w_r;
    const size_t gt_w = (size_t)b * HWSZ + (size_t)h_w * WW + w_w;

    const float scale = 0.17677669529663687f;
    const int ti = tid >> 4;
    const int tj = tid & 15;

    for (int head = 0; head < 8; ++head) {
        const unsigned short* base = qkv + gt_r * 768 + head * 32 + c8;
        ushort4 qa = *(const ushort4*)(base);
        ushort4 qb = *(const ushort4*)(base + 4);
        ushort4 ka = *(const ushort4*)(base + 256);
        ushort4 kb = *(const ushort4*)(base + 260);
        ushort4 va = *(const ushort4*)(base + 512);
        ushort4 vb = *(const ushort4*)(base + 516);
        qs[t][c8 + 0] = bf2f(qa.x) * scale; qs[t][c8 + 1] = bf2f(qa.y) * scale;
        qs[t][c8 + 2] = bf2f(qa.z) * scale; qs[t][c8 + 3] = bf2f(qa.w) * scale;
        qs[t][c8 + 4] = bf2f(qb.x) * scale; qs[t][c8 + 5] = bf2f(qb.y) * scale;
        qs[t][c8 + 6] = bf2f(qb.z) * scale; qs[t][c8 + 7] = bf2f(qb.w) * scale;
        ks[t][c8 + 0] = bf2f(ka.x); ks[t][c8 + 1] = bf2f(ka.y);
        ks[t][c8 + 2] = bf2f(ka.z); ks[t][c8 + 3] = bf2f(ka.w);
        ks[t][c8 + 4] = bf2f(kb.x); ks[t][c8 + 5] = bf2f(kb.y);
        ks[t][c8 + 6] = bf2f(kb.z); ks[t][c8 + 7] = bf2f(kb.w);
        vs[t][c8 + 0] = bf2f(va.x); vs[t][c8 + 1] = bf2f(va.y);
        vs[t][c8 + 2] = bf2f(va.z); vs[t][c8 + 3] = bf2f(va.w);
        vs[t][c8 + 4] = bf2f(vb.x); vs[t][c8 + 5] = bf2f(vb.y);
        vs[t][c8 + 6] = bf2f(vb.z); vs[t][c8 + 7] = bf2f(vb.w);
        __syncthreads();

        float sr[4][4] = {};
#pragma unroll 8
        for (int c = 0; c < 32; ++c) {
            float qv[4], kv[4];
#pragma unroll
            for (int i = 0; i < 4; ++i) qv[i] = qs[ti * 4 + i][c];
#pragma unroll
            for (int j = 0; j < 4; ++j) kv[j] = ks[tj * 4 + j][c];
#pragma unroll
            for (int i = 0; i < 4; ++i)
#pragma unroll
                for (int j = 0; j < 4; ++j)
                    sr[i][j] += qv[i] * kv[j];
        }
#pragma unroll
        for (int i = 0; i < 4; ++i)
#pragma unroll
            for (int j = 0; j < 4; ++j)
                S[ti * 4 + i][tj * 4 + j] = sr[i][j];
        __syncthreads();

        // wave-parallel softmax: 4 threads per row (was 64/256 threads serial)
        {
            const int r  = tid >> 2;
            const int s0 = (tid & 3) * 16;
            float mx = -1e30f;
#pragma unroll
            for (int j = 0; j < 16; ++j) mx = fmaxf(mx, S[r][s0 + j]);
            mx = fmaxf(mx, __shfl_xor(mx, 1));
            mx = fmaxf(mx, __shfl_xor(mx, 2));
            float sum = 0.f;
#pragma unroll
            for (int j = 0; j < 16; ++j) {
                float e = expf(S[r][s0 + j] - mx);
                S[r][s0 + j] = e;
                sum += e;
            }
            sum += __shfl_xor(sum, 1);
            sum += __shfl_xor(sum, 2);
            float inv = 1.f / sum;
#pragma unroll
            for (int j = 0; j < 16; ++j) S[r][s0 + j] *= inv;
        }
        __syncthreads();

        float ov[8] = {};
#pragma unroll 8
        for (int j = 0; j < 64; ++j) {
            float pv = S[t][j];
            const float4 v0 = *(const float4*)&vs[j][c8];
            const float4 v1 = *(const float4*)&vs[j][c8 + 4];
            ov[0] += pv * v0.x; ov[1] += pv * v0.y;
            ov[2] += pv * v0.z; ov[3] += pv * v0.w;
            ov[4] += pv * v1.x; ov[5] += pv * v1.y;
            ov[6] += pv * v1.z; ov[7] += pv * v1.w;
        }
        unsigned short* op = attn_out + gt_w * CC + head * 32 + c8;
        ushort4 o1, o2;
        o1.x = f2bf(ov[0]); o1.y = f2bf(ov[1]); o1.z = f2bf(ov[2]); o1.w = f2bf(ov[3]);
        o2.x = f2bf(ov[4]); o2.y = f2bf(ov[5]); o2.z = f2bf(ov[6]); o2.w = f2bf(ov[7]);
        *(ushort4*)op = o1;
        *(ushort4*)(op + 4) = o2;
        __syncthreads();
    }
}

// ---------------------------------------------------------------------------
extern "C" void kernel_launch(void* const* d_in, const int* in_sizes, int n_in,
                              void* d_out, int out_size, void* d_ws, size_t ws_size,
                              hipStream_t stream)
{
    const void* x      = d_in[0];
    const void* w1     = d_in[1];  const void* b1  = d_in[2];
    const void* w2     = d_in[3];  const void* b2  = d_in[4];
    const void* w3     = d_in[5];  const void* b3  = d_in[6];
    const void* wf     = d_in[7];  const void* bf_ = d_in[8];
    const void* gw     = d_in[9];  const void* bw  = d_in[10];
    const void* wqkv_w = d_in[11]; const void* bqkv_w = d_in[12];
    const void* wo_w   = d_in[13]; const void* bo_w   = d_in[14];
    const void* gg     = d_in[15]; const void* bg  = d_in[16];
    const void* wqkv_g = d_in[17]; const void* bqkv_g = d_in[18];
    const void* wo_g   = d_in[19]; const void* bo_g   = d_in[20];
    const void* gm     = d_in[21]; const void* bm  = d_in[22];
    const void* m1w    = d_in[23]; const void* m1b = d_in[24];
    const void* m2w    = d_in[25]; const void* m2b = d_in[26];

    const size_t MiB = 1048576ull;
    const long long nout = (long long)out_size;

    if (72 * MiB > ws_size) {
        float wsMiB = (float)(ws_size / MiB);
        if (wsMiB > 8192.f) wsMiB = 8192.f;
        report_ws_kernel<<<1024, 256, 0, stream>>>((unsigned short*)d_out, nout, 1024.f + wsMiB);
        return;
    }

    int nb = 8;
    while (nb > 1 && (size_t)nb * 64 * MiB + 8 * MiB > ws_size) nb >>= 1;
    const int nchunks = 8 / nb;
    const int Mc = nb * HWSZ;

    char* ws = (char*)d_ws;
    float*          xs   = (float*)ws;
    unsigned short* regA = (unsigned short*)(ws + (size_t)nb * 16 * MiB);
    unsigned short* xmat = (unsigned short*)(ws + (size_t)nb * 48 * MiB);
    unsigned short* xln  = (unsigned short*)(ws + (size_t)nb * 56 * MiB);
    int*            flags = (int*)(ws + (size_t)nb * 64 * MiB);
    unsigned short* wbf  = (unsigned short*)(ws + (size_t)nb * 64 * MiB + 1 * MiB);
    float*          bcv  = (float*)(ws + (size_t)nb * 64 * MiB + 4 * MiB);

    probe_kernel<<<1, 256, 0, stream>>>((const unsigned short*)x, flags);
    convert_weights_kernel<0><<<1024, 256, 0, stream>>>(wf, wqkv_w, wo_w, wqkv_g, wo_g, m1w, m2w, wbf, flags);
    convert_weights_kernel<1><<<1024, 256, 0, stream>>>(wf, wqkv_w, wo_w, wqkv_g, wo_g, m1w, m2w, wbf, flags);
    convert_bias_kernel<0><<<20, 256, 0, stream>>>(bf_, gw, bw, bqkv_w, bo_w, gg, bg, bqkv_g, bo_g, gm, bm, m1b, m2b, bcv, flags);
    convert_bias_kernel<1><<<20, 256, 0, stream>>>(bf_, gw, bw, bqkv_w, bo_w, gg, bg, bqkv_g, bo_g, gm, bm, m1b, m2b, bcv, flags);

    const int MB = Mc / 128;   // gemm grid y
    for (int c = 0; c < nchunks; ++c) {
        const size_t elemOff = (size_t)c * nb * CC * HWSZ;
        const void* xc0 = (const void*)((const unsigned short*)x + elemOff);
        const void* xc1 = (const void*)((const float*)x + elemOff);
        void* outc0 = (void*)((unsigned short*)d_out + elemOff);
        void* outc1 = (void*)((float*)d_out + elemOff);
        unsigned short* cat  = regA;
        unsigned short* qkvb = regA;
        unsigned short* h1   = regA;
        unsigned short* xm   = xmat;
        unsigned short* attn = xmat;

        transpose_in_kernel<0><<<dim3(256, 4, nb), 256, 0, stream>>>(xc0, xs, flags);
        transpose_in_kernel<1><<<dim3(256, 4, nb), 256, 0, stream>>>(xc1, xs, flags);

        dwconv_cat_kernel<0><<<dim3(64, 256, nb), 256, 0, stream>>>(xc0, w1, b1, w2, b2, w3, b3, cat, Mc, flags);
        dwconv_cat_kernel<1><<<dim3(64, 256, nb), 256, 0, stream>>>(xc1, w1, b1, w2, b2, w3, b3, cat, Mc, flags);

        gemm_mfma_kernel<1, 0><<<dim3(2, MB), 256, 0, stream>>>(cat, wbf + WF_OFF, bcv + BF_OFF, xm, 256, 768, Mc);

        // window branch
        ln_kernel<0><<<Mc / 4, 256, 0, stream>>>(xm, bcv + GW_OFF, bcv + BW_OFF, xln);
        gemm_mfma_kernel<0, 0><<<dim3(6, MB), 256, 0, stream>>>(xln, wbf + WQW_OFF, bcv + BQW_OFF, qkvb, 768, 256, 0);
        attn_kernel<0><<<nb * 256, 256, 0, stream>>>(qkvb, attn);
        gemm_mfma_kernel<0, 2><<<dim3(2, MB), 256, 0, stream>>>(attn, wbf + WOW_OFF, bcv + BOW_OFF, xs, 256, 256, 0);

        // grid branch
        ln_kernel<1><<<Mc / 4, 256, 0, stream>>>(xs, bcv + GG_OFF, bcv + BG_OFF, xln);
        gemm_mfma_kernel<0, 0><<<dim3(6, MB), 256, 0, stream>>>(xln, wbf + WQG_OFF, bcv + BQG_OFF, qkvb, 768, 256, 0);
        attn_kernel<1><<<nb * 256, 256, 0, stream>>>(qkvb, attn);
        gemm_mfma_kernel<0, 2><<<dim3(2, MB), 256, 0, stream>>>(attn, wbf + WOG_OFF, bcv + BOG_OFF, xs, 256, 256, 0);

        // MLP
        ln_kernel<1><<<Mc / 4, 256, 0, stream>>>(xs, bcv + GM_OFF, bcv + BM_OFF, xln);
        gemm_mfma_kernel<0, 1><<<dim3(8, MB), 256, 0, stream>>>(xln, wbf + M1W_OFF, bcv + M1B_OFF, h1, 1024, 256, 0);
        gemm_mfma_kernel<0, 2><<<dim3(2, MB), 256, 0, stream>>>(h1, wbf + M2W_OFF, bcv + M2B_OFF, xs, 256, 1024, 0);

        transpose_out_kernel<0><<<dim3(256, 4, nb), 256, 0, stream>>>(xs, outc0, flags);
        transpose_out_kernel<1><<<dim3(256, 4, nb), 256, 0, stream>>>(xs, outc1, flags);
    }
}

// Round 2
// 1841.682 us; speedup vs baseline: 1.8980x; 1.1421x over previous
//
#include <hip/hip_runtime.h>
#include <hip/hip_bf16.h>
#include <math.h>

// ---------------------------------------------------------------------------
// MultiScaleWindowGridTransformer: B=8, C=256, H=W=128, WS=8, NH=8, HD=32
// Round 6: MFMA attention (coalesced single-pass qkv staging, in-register
// softmax, P/Vt LDS round-trip), dwconv 8-row blocks + vectorized loads.
// GEMM path unchanged from round 5 (global_load_lds width=16, XCD swizzle).
// ---------------------------------------------------------------------------

#define CC 256
#define HH 128
#define WW 128
#define HWSZ 16384

typedef __attribute__((ext_vector_type(8))) short short8v;   // 8 bf16 (4 VGPRs)
typedef __attribute__((ext_vector_type(4))) float float4v;   // MFMA C/D frag

#if defined(__has_builtin)
#if __has_builtin(__builtin_amdgcn_global_load_lds)
#define USE_GLDS 1
#endif
#endif
#ifndef USE_GLDS
#define USE_GLDS 0
#endif

static __device__ __forceinline__ float bf2f(unsigned short u) {
    union { float f; unsigned int i; } x; x.i = ((unsigned int)u) << 16; return x.f;
}
static __device__ __forceinline__ unsigned short f2bf(float f) {
    union { float f; unsigned int i; } x; x.f = f;
    unsigned int r = x.i + 0x7FFFu + ((x.i >> 16) & 1u);   // RNE
    return (unsigned short)(r >> 16);
}
template<int FMT> static __device__ __forceinline__ float ldin(const void* p, size_t i) {
    if (FMT == 0) return bf2f(((const unsigned short*)p)[i]);
    return ((const float*)p)[i];
}

#if USE_GLDS
static __device__ __forceinline__ void gload16(const unsigned short* g, unsigned short* l) {
    // HW semantics (guide m104): LDS dest = wave-uniform base + lane*16B; global src per-lane.
    __builtin_amdgcn_global_load_lds(
        (const __attribute__((address_space(1))) unsigned int*)g,
        (__attribute__((address_space(3))) unsigned int*)l, 16, 0, 0);
}
#endif

// --------------------------- format probe ----------------------------------
__global__ void probe_kernel(const unsigned short* x, int* flags) {
    __shared__ int mx[256];
    int m = 0;
    for (int i = threadIdx.x; i < 65536; i += 256) {
        int e = (x[i] >> 7) & 0xFF;
        m = m > e ? m : e;
    }
    mx[threadIdx.x] = m; __syncthreads();
    for (int s = 128; s > 0; s >>= 1) {
        if (threadIdx.x < s) mx[threadIdx.x] = mx[threadIdx.x] > mx[threadIdx.x + s] ? mx[threadIdx.x] : mx[threadIdx.x + s];
        __syncthreads();
    }
    if (threadIdx.x == 0) flags[0] = (mx[0] > 200) ? 1 : 0;
}
__global__ void report_ws_kernel(unsigned short* out, long long n, float code) {
    long long i = (long long)blockIdx.x * blockDim.x + threadIdx.x;
    const long long st = (long long)gridDim.x * blockDim.x;
    unsigned short c = f2bf(code);
    for (; i < n; i += st) out[i] = c;
}

// --------------------------- weight normalization --------------------------
#define WF_OFF   0
#define WQW_OFF  196608
#define WOW_OFF  393216
#define WQG_OFF  458752
#define WOG_OFF  655360
#define M1W_OFF  720896
#define M2W_OFF  983040
#define WTOT     1245184
#define BF_OFF   0
#define GW_OFF   256
#define BW_OFF   512
#define BQW_OFF  768
#define BOW_OFF  1536
#define GG_OFF   1792
#define BG_OFF   2048
#define BQG_OFF  2304
#define BOG_OFF  3072
#define GM_OFF   3328
#define BM_OFF   3584
#define M1B_OFF  3840
#define M2B_OFF  4864
#define BTOT     5120

template<int FMT>
__global__ __launch_bounds__(256) void convert_weights_kernel(
    const void* __restrict__ wf, const void* __restrict__ wqkv_w, const void* __restrict__ wo_w,
    const void* __restrict__ wqkv_g, const void* __restrict__ wo_g,
    const void* __restrict__ m1w, const void* __restrict__ m2w,
    unsigned short* __restrict__ out, const int* __restrict__ flags)
{
    if (flags[0] != FMT) return;
    int i = blockIdx.x * 256 + threadIdx.x;
    const int st = gridDim.x * 256;
    for (; i < WTOT; i += st) {
        const void* src; int off;
        if (i < WQW_OFF)      { src = wf;     off = i; }
        else if (i < WOW_OFF) { src = wqkv_w; off = i - WQW_OFF; }
        else if (i < WQG_OFF) { src = wo_w;   off = i - WOW_OFF; }
        else if (i < WOG_OFF) { src = wqkv_g; off = i - WQG_OFF; }
        else if (i < M1W_OFF) { src = wo_g;   off = i - WOG_OFF; }
        else if (i < M2W_OFF) { src = m1w;    off = i - M1W_OFF; }
        else                  { src = m2w;    off = i - M2W_OFF; }
        out[i] = (FMT == 0) ? ((const unsigned short*)src)[off]
                            : f2bf(((const float*)src)[off]);
    }
}

template<int FMT>
__global__ __launch_bounds__(256) void convert_bias_kernel(
    const void* bf_, const void* gw, const void* bw, const void* bqkv_w, const void* bo_w,
    const void* gg, const void* bg, const void* bqkv_g, const void* bo_g,
    const void* gm, const void* bm, const void* m1b, const void* m2b,
    float* __restrict__ out, const int* __restrict__ flags)
{
    if (flags[0] != FMT) return;
    int i = blockIdx.x * 256 + threadIdx.x;
    if (i >= BTOT) return;
    const void* src; int off;
    if (i < GW_OFF)        { src = bf_;    off = i; }
    else if (i < BW_OFF)   { src = gw;     off = i - GW_OFF; }
    else if (i < BQW_OFF)  { src = bw;     off = i - BW_OFF; }
    else if (i < BOW_OFF)  { src = bqkv_w; off = i - BQW_OFF; }
    else if (i < GG_OFF)   { src = bo_w;   off = i - BOW_OFF; }
    else if (i < BG_OFF)   { src = gg;     off = i - GG_OFF; }
    else if (i < BQG_OFF)  { src = bg;     off = i - BG_OFF; }
    else if (i < BOG_OFF)  { src = bqkv_g; off = i - BQG_OFF; }
    else if (i < GM_OFF)   { src = bo_g;   off = i - BOG_OFF; }
    else if (i < BM_OFF)   { src = gm;     off = i - GM_OFF; }
    else if (i < M1B_OFF)  { src = bm;     off = i - BM_OFF; }
    else if (i < M2B_OFF)  { src = m1b;    off = i - M1B_OFF; }
    else                   { src = m2b;    off = i - M2B_OFF; }
    out[i] = ldin<FMT>(src, off);
}

// --------------------------- pipeline kernels ------------------------------
template<int FMT>
__global__ __launch_bounds__(256) void transpose_in_kernel(
    const void* __restrict__ in, float* __restrict__ out, const int* __restrict__ flags)
{
    if (flags[0] != FMT) return;
    __shared__ float tile[64][65];
    const int b  = blockIdx.z;
    const int s0 = blockIdx.x * 64;
    const int r0 = blockIdx.y * 64;
    const int tx = threadIdx.x & 63;
    const int ty = threadIdx.x >> 6;
    const size_t sb = (size_t)b * CC * HWSZ;
    float* dst = out + (size_t)b * HWSZ * CC;
#pragma unroll
    for (int rr = 0; rr < 16; ++rr) {
        int row = ty + rr * 4;
        tile[row][tx] = ldin<FMT>(in, sb + (size_t)(r0 + row) * HWSZ + s0 + tx);
    }
    __syncthreads();
#pragma unroll
    for (int rr = 0; rr < 16; ++rr) {
        int srow = ty + rr * 4;
        dst[(size_t)(s0 + srow) * CC + r0 + tx] = tile[tx][srow];
    }
}

template<int FMT>
__global__ __launch_bounds__(256) void transpose_out_kernel(
    const float* __restrict__ in, void* __restrict__ out, const int* __restrict__ flags)
{
    if (flags[0] != FMT) return;
    __shared__ float tile[64][65];
    const int b  = blockIdx.z;
    const int h0 = blockIdx.x * 64;
    const int c0 = blockIdx.y * 64;
    const int tx = threadIdx.x & 63;
    const int ty = threadIdx.x >> 6;
    const float* src = in + (size_t)b * HWSZ * CC;
    const size_t db = (size_t)b * CC * HWSZ;
#pragma unroll
    for (int rr = 0; rr < 16; ++rr) {
        int row = ty + rr * 4;
        tile[row][tx] = src[(size_t)(h0 + row) * CC + c0 + tx];
    }
    __syncthreads();
#pragma unroll
    for (int rr = 0; rr < 16; ++rr) {
        int crow = ty + rr * 4;
        size_t di = db + (size_t)(c0 + crow) * HWSZ + h0 + tx;
        float v = tile[tx][crow];
        if (FMT) ((float*)out)[di] = v;
        else ((unsigned short*)out)[di] = f2bf(v);
    }
}

// dwconv: 8 output rows per block, vectorized interior loads, 4 outputs/thread.
template<int FMT>
__global__ __launch_bounds__(256) void dwconv_cat_kernel(
    const void* __restrict__ x,
    const void* __restrict__ w1, const void* __restrict__ b1,
    const void* __restrict__ w2, const void* __restrict__ b2,
    const void* __restrict__ w3, const void* __restrict__ b3,
    unsigned short* __restrict__ cat, int Mc, const int* __restrict__ flags)
{
    if (flags[0] != FMT) return;
    __shared__ float patch[14][140];   // rows h0-3..h0+10, col gw+4 (cols 1..134 used)
    __shared__ float wt[83];
    const int hb = blockIdx.x;
    const int c  = blockIdx.y;
    const int b  = blockIdx.z;
    const int tid = threadIdx.x;

    if (tid < 83) {
        float v;
        if (tid < 9)       v = ldin<FMT>(w1, c * 9 + tid);
        else if (tid < 34) v = ldin<FMT>(w2, c * 25 + (tid - 9));
        else               v = ldin<FMT>(w3, c * 49 + (tid - 34));
        wt[tid] = v;
    }
    const int h0 = hb * 8;
    const size_t xb = ((size_t)b * CC + c) * HWSZ;

    // interior: 14 rows x 32 chunks of 4 (gw = c4..c4+3 -> patch col gw+4)
    for (int i = tid; i < 448; i += 256) {
        const int r  = i >> 5;
        const int c4 = (i & 31) * 4;
        const int gh = h0 - 3 + r;
        float4 vv;
        if (gh >= 0 && gh < HH) {
            if (FMT == 0) {
                ushort4 u = *(const ushort4*)((const unsigned short*)x + xb + (size_t)gh * WW + c4);
                vv.x = bf2f(u.x); vv.y = bf2f(u.y); vv.z = bf2f(u.z); vv.w = bf2f(u.w);
            } else {
                vv = *(const float4*)((const float*)x + xb + (size_t)gh * WW + c4);
            }
        } else { vv.x = vv.y = vv.z = vv.w = 0.f; }
        *(float4*)&patch[r][c4 + 4] = vv;
    }
    // halo: 14 rows x 6 cols (gw -3..-1 -> col 1..3, gw 128..130 -> col 132..134)
    for (int i = tid; i < 84; i += 256) {
        const int r = i / 6, j = i % 6;
        const int gh = h0 - 3 + r;
        const int gw = (j < 3) ? (j - 3) : (125 + j);
        float v = 0.f;
        if (gh >= 0 && gh < HH && gw >= 0 && gw < WW)
            v = ldin<FMT>(x, xb + (size_t)gh * WW + gw);
        patch[r][gw + 4] = v;
    }
    __syncthreads();

    const int w  = tid & 127;
    const int rb = (tid >> 7) * 4;
    const float bb1 = ldin<FMT>(b1, c), bb2 = ldin<FMT>(b2, c), bb3 = ldin<FMT>(b3, c);

#pragma unroll
    for (int ri = 0; ri < 4; ++ri) {
        const int row = rb + ri;
        const int pr  = row + 3;
        float s1 = bb1, s2 = bb2, s3 = bb3;
#pragma unroll
        for (int dy = -1; dy <= 1; ++dy)
#pragma unroll
            for (int dx = -1; dx <= 1; ++dx)
                s1 += patch[pr + dy][w + 4 + dx] * wt[(dy + 1) * 3 + (dx + 1)];
#pragma unroll
        for (int dy = -2; dy <= 2; ++dy)
#pragma unroll
            for (int dx = -2; dx <= 2; ++dx)
                s2 += patch[pr + dy][w + 4 + dx] * wt[9 + (dy + 2) * 5 + (dx + 2)];
#pragma unroll
        for (int dy = -3; dy <= 3; ++dy)
#pragma unroll
            for (int dx = -3; dx <= 3; ++dx)
                s3 += patch[pr + dy][w + 4 + dx] * wt[34 + (dy + 3) * 7 + (dx + 3)];

        const size_t m = (size_t)b * HWSZ + (size_t)(h0 + row) * WW + w;
        cat[(size_t)c * Mc + m]         = f2bf(s1);
        cat[(size_t)(256 + c) * Mc + m] = f2bf(s2);
        cat[(size_t)(512 + c) * Mc + m] = f2bf(s3);
    }
}

// ---------------------------------------------------------------------------
// MFMA GEMM (unchanged from round 5): C[M,N] = A*W^T + bias, W bf16 [N][K].
// ---------------------------------------------------------------------------
template<int ALAYOUT, int EPI>
__global__ __launch_bounds__(256) void gemm_mfma_kernel(
    const unsigned short* __restrict__ A, const unsigned short* __restrict__ Bw,
    const float* __restrict__ bias, void* __restrict__ Cout,
    int N, int K, int lda)
{
    constexpr int ASTR = ALAYOUT ? 72 : 64;
    __shared__ unsigned short As[128 * ASTR];
    __shared__ unsigned short Bs[128 * 64];
    const int tid  = threadIdx.x;
    const int lane = tid & 63;
    const int wv   = tid >> 6;
    const int wm   = (wv >> 1) * 64;
    const int wn   = (wv & 1) * 64;
    const int l15  = lane & 15;
    const int quad = lane >> 4;

    const int nbx = gridDim.x;
    const int nwg = nbx * gridDim.y;
    const int bid = blockIdx.y * nbx + blockIdx.x;
    const int swz = (bid & 7) * (nwg >> 3) + (bid >> 3);
    const int m0 = (swz / nbx) * 128;
    const int n0 = (swz % nbx) * 128;

    const int sr   = lane >> 3;
    const int scol = (lane & 7) * 8;

    float4v acc[4][4] = {};

    for (int k0 = 0; k0 < K; k0 += 64) {
        __syncthreads();
        if (ALAYOUT == 0) {
            const unsigned short* ga = A + (size_t)(m0 + wv * 32 + sr) * K + k0 + scol;
#pragma unroll
            for (int p = 0; p < 4; ++p) {
                unsigned short* lb = &As[(wv * 32 + p * 8) * 64];
#if USE_GLDS
                gload16(ga + (size_t)(p * 8) * K, lb);
#else
                *(short8v*)(lb + lane * 8) = *(const short8v*)(ga + (size_t)(p * 8) * K);
#endif
            }
        } else {
#pragma unroll
            for (int p = 0; p < 4; ++p) {
                const int k  = p * 16 + (tid >> 4);
                const int mm = (tid & 15) * 8;
                const unsigned short* g = A + (size_t)(k0 + k) * lda + m0 + mm;
                ushort4 va = *(const ushort4*)g;
                ushort4 vb = *(const ushort4*)(g + 4);
                As[(mm + 0) * 72 + k] = va.x; As[(mm + 1) * 72 + k] = va.y;
                As[(mm + 2) * 72 + k] = va.z; As[(mm + 3) * 72 + k] = va.w;
                As[(mm + 4) * 72 + k] = vb.x; As[(mm + 5) * 72 + k] = vb.y;
                As[(mm + 6) * 72 + k] = vb.z; As[(mm + 7) * 72 + k] = vb.w;
            }
        }
        {
            const unsigned short* gb = Bw + (size_t)(n0 + wv * 32 + sr) * K + k0 + scol;
#pragma unroll
            for (int p = 0; p < 4; ++p) {
                unsigned short* lb = &Bs[(wv * 32 + p * 8) * 64];
#if USE_GLDS
                gload16(gb + (size_t)(p * 8) * K, lb);
#else
                *(short8v*)(lb + lane * 8) = *(const short8v*)(gb + (size_t)(p * 8) * K);
#endif
            }
        }
#if USE_GLDS
        asm volatile("s_waitcnt vmcnt(0)" ::: "memory");
#endif
        __syncthreads();

#pragma unroll
        for (int ks = 0; ks < 64; ks += 32) {
            short8v af[4], bfv[4];
#pragma unroll
            for (int i = 0; i < 4; ++i)
                af[i] = *(const short8v*)&As[(wm + i * 16 + l15) * ASTR + ks + quad * 8];
#pragma unroll
            for (int i = 0; i < 4; ++i)
                bfv[i] = *(const short8v*)&Bs[(wn + i * 16 + l15) * 64 + ks + quad * 8];
#pragma unroll
            for (int mi = 0; mi < 4; ++mi)
#pragma unroll
                for (int ni = 0; ni < 4; ++ni)
                    acc[mi][ni] = __builtin_amdgcn_mfma_f32_16x16x32_bf16(
                        af[mi], bfv[ni], acc[mi][ni], 0, 0, 0);
        }
    }

    float bv[4];
#pragma unroll
    for (int ni = 0; ni < 4; ++ni) bv[ni] = bias[n0 + wn + ni * 16 + l15];

#pragma unroll
    for (int mi = 0; mi < 4; ++mi) {
#pragma unroll
        for (int r = 0; r < 4; ++r) {
            const size_t row = (size_t)(m0 + wm + mi * 16 + quad * 4 + r);
#pragma unroll
            for (int ni = 0; ni < 4; ++ni) {
                const int col = n0 + wn + ni * 16 + l15;
                float v = acc[mi][ni][r] + bv[ni];
                if (EPI == 0) {
                    ((unsigned short*)Cout)[row * N + col] = f2bf(v);
                } else if (EPI == 1) {
                    float g = 0.5f * v * (1.0f + erff(v * 0.70710678118654752f));
                    ((unsigned short*)Cout)[row * N + col] = f2bf(g);
                } else {
                    ((float*)Cout)[row * N + col] += v;
                }
            }
        }
    }
}

// LayerNorm over C=256.
template<int FIN>
__global__ __launch_bounds__(256) void ln_kernel(
    const void* __restrict__ inv, const float* __restrict__ g,
    const float* __restrict__ b, unsigned short* __restrict__ out)
{
    const int lane = threadIdx.x & 63;
    const int wv   = threadIdx.x >> 6;
    const size_t m = (size_t)blockIdx.x * 4 + wv;
    const int c0 = lane * 4;
    float v[4];
    if (FIN == 0) {
        ushort4 u = *(const ushort4*)((const unsigned short*)inv + m * CC + c0);
        v[0] = bf2f(u.x); v[1] = bf2f(u.y); v[2] = bf2f(u.z); v[3] = bf2f(u.w);
    } else {
        float4 f = *(const float4*)((const float*)inv + m * CC + c0);
        v[0] = f.x; v[1] = f.y; v[2] = f.z; v[3] = f.w;
    }
    float s  = v[0] + v[1] + v[2] + v[3];
    float sq = v[0]*v[0] + v[1]*v[1] + v[2]*v[2] + v[3]*v[3];
#pragma unroll
    for (int off = 32; off > 0; off >>= 1) {
        s  += __shfl_xor(s,  off);
        sq += __shfl_xor(sq, off);
    }
    const float mean = s * 0.00390625f;
    float var = sq * 0.00390625f - mean * mean;
    if (var < 0.f) var = 0.f;
    const float rs = rsqrtf(var + 1e-5f);
    ushort4 o;
    o.x = f2bf((v[0] - mean) * rs * g[c0 + 0] + b[c0 + 0]);
    o.y = f2bf((v[1] - mean) * rs * g[c0 + 1] + b[c0 + 1]);
    o.z = f2bf((v[2] - mean) * rs * g[c0 + 2] + b[c0 + 2]);
    o.w = f2bf((v[3] - mean) * rs * g[c0 + 3] + b[c0 + 3]);
    *(ushort4*)(out + m * CC + c0) = o;
}

// ---------------------------------------------------------------------------
// MFMA windowed attention. 1 block = 1 window (64 tokens), 4 waves.
// Heads processed in 4 groups of 2; qkv for the group staged once, coalesced.
// QK^T: wave wv owns m-rows 16wv..16wv+15 (1 A-frag, 4 B-frags, 4 MFMA).
// Softmax in C/D frags (rows m=quad*4+r spread over l15 x ni): in-lane +
// shfl_xor{1,2,4,8} reductions. P -> LDS (wave-private rows), Vt built once
// per head ([d][tok], stride 72), PV = 4 MFMA per wave via b128 frag reads.
// Frag maps identical to the verified GEMM above.
// ---------------------------------------------------------------------------
template<int MODE>
__global__ __launch_bounds__(256) void attn_kernel(
    const unsigned short* __restrict__ qkv, unsigned short* __restrict__ attn_out)
{
    __shared__ unsigned short q_lds[64 * 72];
    __shared__ unsigned short k_lds[64 * 72];
    __shared__ unsigned short v_lds[64 * 72];
    __shared__ unsigned short vt_lds[32 * 72];
    __shared__ unsigned short p_lds[64 * 72];

    const int tid  = threadIdx.x;
    const int lane = tid & 63;
    const int wv   = tid >> 6;
    const int l15  = lane & 15;
    const int quad = lane >> 4;
    const int wi   = blockIdx.x;
    const int b    = wi >> 8;
    const int rem  = wi & 255;
    const int i2   = rem >> 4;
    const int j2   = rem & 15;

    const float scale = 0.17677669529663687f;

    auto gt_read = [&](int tok) -> size_t {
        const int p = tok >> 3, qq = tok & 7;
        int h_r, w_r;
        if (MODE == 0) { h_r = i2 * 8 + p;  w_r = j2 * 8 + qq; }
        else           { h_r = p * 16 + i2; w_r = qq * 16 + j2; }
        return (size_t)b * HWSZ + (size_t)h_r * WW + w_r;
    };
    auto gt_write = [&](int tok) -> size_t {
        const int p = tok >> 3, qq = tok & 7;
        int h_w, w_w;
        if (MODE == 0) { h_w = i2 * 8 + p; w_w = j2 * 8 + qq; }
        else { h_w = j2 * 8 + (i2 >> 1); w_w = (i2 & 1) * 64 + p * 8 + qq; }
        return (size_t)b * HWSZ + (size_t)h_w * WW + w_w;
    };

    for (int g = 0; g < 4; ++g) {
        // stage q/k/v channel slice [g*64, g*64+64) for all 64 tokens, coalesced 16B
        for (int v = tid; v < 512; v += 256) {
            const int tok = v >> 3;
            const int cg  = (v & 7) * 8;
            const unsigned short* src = qkv + gt_read(tok) * 768 + g * 64 + cg;
            *(short8v*)&q_lds[tok * 72 + cg] = *(const short8v*)(src);
            *(short8v*)&k_lds[tok * 72 + cg] = *(const short8v*)(src + 256);
            *(short8v*)&v_lds[tok * 72 + cg] = *(const short8v*)(src + 512);
        }
        __syncthreads();

#pragma unroll
        for (int hl = 0; hl < 2; ++hl) {
            // ---- build Vt[d][tok] for this head: wave wv handles d rows wv*8..wv*8+7
            {
                const int tok = lane;
                const int dg  = wv * 8;
                short8v vv = *(const short8v*)&v_lds[tok * 72 + hl * 32 + dg];
#pragma unroll
                for (int j = 0; j < 8; ++j)
                    vt_lds[(dg + j) * 72 + tok] = (unsigned short)vv[j];
            }

            // ---- QK^T: S[m][n] for m-rows 16wv..16wv+15
            short8v af = *(const short8v*)&q_lds[(16 * wv + l15) * 72 + hl * 32 + quad * 8];
            float4v s[4];
#pragma unroll
            for (int ni = 0; ni < 4; ++ni) {
                short8v bfv = *(const short8v*)&k_lds[(16 * ni + l15) * 72 + hl * 32 + quad * 8];
                float4v z = {};
                s[ni] = __builtin_amdgcn_mfma_f32_16x16x32_bf16(af, bfv, z, 0, 0, 0);
            }

            // ---- softmax rows m = 16wv + quad*4 + r
#pragma unroll
            for (int r = 0; r < 4; ++r) {
                float m1 = fmaxf(fmaxf(s[0][r], s[1][r]), fmaxf(s[2][r], s[3][r]));
#pragma unroll
                for (int off = 1; off < 16; off <<= 1) m1 = fmaxf(m1, __shfl_xor(m1, off));
                const float rowmax = m1 * scale;
                float sum = 0.f;
#pragma unroll
                for (int ni = 0; ni < 4; ++ni) {
                    const float e = __expf(s[ni][r] * scale - rowmax);
                    s[ni][r] = e; sum += e;
                }
#pragma unroll
                for (int off = 1; off < 16; off <<= 1) sum += __shfl_xor(sum, off);
                const float inv = 1.f / sum;
#pragma unroll
                for (int ni = 0; ni < 4; ++ni) s[ni][r] *= inv;
            }

            // ---- P -> LDS (bf16), rows are wave-private
#pragma unroll
            for (int ni = 0; ni < 4; ++ni)
#pragma unroll
                for (int r = 0; r < 4; ++r)
                    p_lds[(16 * wv + quad * 4 + r) * 72 + ni * 16 + l15] = f2bf(s[ni][r]);

            __syncthreads();   // Vt + P visible

            // ---- PV: O[m][d] = sum_n P[m][n] * Vt[d][n]
            float4v o[2] = {};
#pragma unroll
            for (int kk = 0; kk < 2; ++kk) {
                short8v pf = *(const short8v*)&p_lds[(16 * wv + l15) * 72 + kk * 32 + quad * 8];
#pragma unroll
                for (int dt = 0; dt < 2; ++dt) {
                    short8v vf = *(const short8v*)&vt_lds[(dt * 16 + l15) * 72 + kk * 32 + quad * 8];
                    o[dt] = __builtin_amdgcn_mfma_f32_16x16x32_bf16(pf, vf, o[dt], 0, 0, 0);
                }
            }

            // ---- store O rows
            const int head = g * 2 + hl;
#pragma unroll
            for (int r = 0; r < 4; ++r) {
                const int tok = 16 * wv + quad * 4 + r;
                unsigned short* op = attn_out + gt_write(tok) * CC + head * 32;
                op[l15]      = f2bf(o[0][r]);
                op[16 + l15] = f2bf(o[1][r]);
            }
            __syncthreads();   // PV reads done before next Vt/stage overwrite
        }
    }
}

// ---------------------------------------------------------------------------
extern "C" void kernel_launch(void* const* d_in, const int* in_sizes, int n_in,
                              void* d_out, int out_size, void* d_ws, size_t ws_size,
                              hipStream_t stream)
{
    const void* x      = d_in[0];
    const void* w1     = d_in[1];  const void* b1  = d_in[2];
    const void* w2     = d_in[3];  const void* b2  = d_in[4];
    const void* w3     = d_in[5];  const void* b3  = d_in[6];
    const void* wf     = d_in[7];  const void* bf_ = d_in[8];
    const void* gw     = d_in[9];  const void* bw  = d_in[10];
    const void* wqkv_w = d_in[11]; const void* bqkv_w = d_in[12];
    const void* wo_w   = d_in[13]; const void* bo_w   = d_in[14];
    const void* gg     = d_in[15]; const void* bg  = d_in[16];
    const void* wqkv_g = d_in[17]; const void* bqkv_g = d_in[18];
    const void* wo_g   = d_in[19]; const void* bo_g   = d_in[20];
    const void* gm     = d_in[21]; const void* bm  = d_in[22];
    const void* m1w    = d_in[23]; const void* m1b = d_in[24];
    const void* m2w    = d_in[25]; const void* m2b = d_in[26];

    const size_t MiB = 1048576ull;
    const long long nout = (long long)out_size;

    if (72 * MiB > ws_size) {
        float wsMiB = (float)(ws_size / MiB);
        if (wsMiB > 8192.f) wsMiB = 8192.f;
        report_ws_kernel<<<1024, 256, 0, stream>>>((unsigned short*)d_out, nout, 1024.f + wsMiB);
        return;
    }

    int nb = 8;
    while (nb > 1 && (size_t)nb * 64 * MiB + 8 * MiB > ws_size) nb >>= 1;
    const int nchunks = 8 / nb;
    const int Mc = nb * HWSZ;

    char* ws = (char*)d_ws;
    float*          xs   = (float*)ws;
    unsigned short* regA = (unsigned short*)(ws + (size_t)nb * 16 * MiB);
    unsigned short* xmat = (unsigned short*)(ws + (size_t)nb * 48 * MiB);
    unsigned short* xln  = (unsigned short*)(ws + (size_t)nb * 56 * MiB);
    int*            flags = (int*)(ws + (size_t)nb * 64 * MiB);
    unsigned short* wbf  = (unsigned short*)(ws + (size_t)nb * 64 * MiB + 1 * MiB);
    float*          bcv  = (float*)(ws + (size_t)nb * 64 * MiB + 4 * MiB);

    probe_kernel<<<1, 256, 0, stream>>>((const unsigned short*)x, flags);
    convert_weights_kernel<0><<<1024, 256, 0, stream>>>(wf, wqkv_w, wo_w, wqkv_g, wo_g, m1w, m2w, wbf, flags);
    convert_weights_kernel<1><<<1024, 256, 0, stream>>>(wf, wqkv_w, wo_w, wqkv_g, wo_g, m1w, m2w, wbf, flags);
    convert_bias_kernel<0><<<20, 256, 0, stream>>>(bf_, gw, bw, bqkv_w, bo_w, gg, bg, bqkv_g, bo_g, gm, bm, m1b, m2b, bcv, flags);
    convert_bias_kernel<1><<<20, 256, 0, stream>>>(bf_, gw, bw, bqkv_w, bo_w, gg, bg, bqkv_g, bo_g, gm, bm, m1b, m2b, bcv, flags);

    const int MB = Mc / 128;
    for (int c = 0; c < nchunks; ++c) {
        const size_t elemOff = (size_t)c * nb * CC * HWSZ;
        const void* xc0 = (const void*)((const unsigned short*)x + elemOff);
        const void* xc1 = (const void*)((const float*)x + elemOff);
        void* outc0 = (void*)((unsigned short*)d_out + elemOff);
        void* outc1 = (void*)((float*)d_out + elemOff);
        unsigned short* cat  = regA;
        unsigned short* qkvb = regA;
        unsigned short* h1   = regA;
        unsigned short* xm   = xmat;
        unsigned short* attn = xmat;

        transpose_in_kernel<0><<<dim3(256, 4, nb), 256, 0, stream>>>(xc0, xs, flags);
        transpose_in_kernel<1><<<dim3(256, 4, nb), 256, 0, stream>>>(xc1, xs, flags);

        dwconv_cat_kernel<0><<<dim3(16, 256, nb), 256, 0, stream>>>(xc0, w1, b1, w2, b2, w3, b3, cat, Mc, flags);
        dwconv_cat_kernel<1><<<dim3(16, 256, nb), 256, 0, stream>>>(xc1, w1, b1, w2, b2, w3, b3, cat, Mc, flags);

        gemm_mfma_kernel<1, 0><<<dim3(2, MB), 256, 0, stream>>>(cat, wbf + WF_OFF, bcv + BF_OFF, xm, 256, 768, Mc);

        // window branch
        ln_kernel<0><<<Mc / 4, 256, 0, stream>>>(xm, bcv + GW_OFF, bcv + BW_OFF, xln);
        gemm_mfma_kernel<0, 0><<<dim3(6, MB), 256, 0, stream>>>(xln, wbf + WQW_OFF, bcv + BQW_OFF, qkvb, 768, 256, 0);
        attn_kernel<0><<<nb * 256, 256, 0, stream>>>(qkvb, attn);
        gemm_mfma_kernel<0, 2><<<dim3(2, MB), 256, 0, stream>>>(attn, wbf + WOW_OFF, bcv + BOW_OFF, xs, 256, 256, 0);

        // grid branch
        ln_kernel<1><<<Mc / 4, 256, 0, stream>>>(xs, bcv + GG_OFF, bcv + BG_OFF, xln);
        gemm_mfma_kernel<0, 0><<<dim3(6, MB), 256, 0, stream>>>(xln, wbf + WQG_OFF, bcv + BQG_OFF, qkvb, 768, 256, 0);
        attn_kernel<1><<<nb * 256, 256, 0, stream>>>(qkvb, attn);
        gemm_mfma_kernel<0, 2><<<dim3(2, MB), 256, 0, stream>>>(attn, wbf + WOG_OFF, bcv + BOG_OFF, xs, 256, 256, 0);

        // MLP
        ln_kernel<1><<<Mc / 4, 256, 0, stream>>>(xs, bcv + GM_OFF, bcv + BM_OFF, xln);
        gemm_mfma_kernel<0, 1><<<dim3(8, MB), 256, 0, stream>>>(xln, wbf + M1W_OFF, bcv + M1B_OFF, h1, 1024, 256, 0);
        gemm_mfma_kernel<0, 2><<<dim3(2, MB), 256, 0, stream>>>(h1, wbf + M2W_OFF, bcv + M2B_OFF, xs, 256, 1024, 0);

        transpose_out_kernel<0><<<dim3(256, 4, nb), 256, 0, stream>>>(xs, outc0, flags);
        transpose_out_kernel<1><<<dim3(256, 4, nb), 256, 0, stream>>>(xs, outc1, flags);
    }
}

// Round 3
// 1767.192 us; speedup vs baseline: 1.9780x; 1.0422x over previous
//
#include <hip/hip_runtime.h>
#include <hip/hip_bf16.h>
#include <math.h>

// ---------------------------------------------------------------------------
// MultiScaleWindowGridTransformer: B=8, C=256, H=W=128, WS=8, NH=8, HD=32
// Round 7: dwconv register-window rewrite (3x ds_read_b128 per input row,
// scalar-uniform weights from f32 arena, ushort4 stores), vectorized
// transpose global access. GEMM/attn unchanged from round 6.
// ---------------------------------------------------------------------------

#define CC 256
#define HH 128
#define WW 128
#define HWSZ 16384

typedef __attribute__((ext_vector_type(8))) short short8v;   // 8 bf16 (4 VGPRs)
typedef __attribute__((ext_vector_type(4))) float float4v;   // MFMA C/D frag

#if defined(__has_builtin)
#if __has_builtin(__builtin_amdgcn_global_load_lds)
#define USE_GLDS 1
#endif
#endif
#ifndef USE_GLDS
#define USE_GLDS 0
#endif

static __device__ __forceinline__ float bf2f(unsigned short u) {
    union { float f; unsigned int i; } x; x.i = ((unsigned int)u) << 16; return x.f;
}
static __device__ __forceinline__ unsigned short f2bf(float f) {
    union { float f; unsigned int i; } x; x.f = f;
    unsigned int r = x.i + 0x7FFFu + ((x.i >> 16) & 1u);   // RNE
    return (unsigned short)(r >> 16);
}
template<int FMT> static __device__ __forceinline__ float ldin(const void* p, size_t i) {
    if (FMT == 0) return bf2f(((const unsigned short*)p)[i]);
    return ((const float*)p)[i];
}

#if USE_GLDS
static __device__ __forceinline__ void gload16(const unsigned short* g, unsigned short* l) {
    // HW semantics (guide m104): LDS dest = wave-uniform base + lane*16B; global src per-lane.
    __builtin_amdgcn_global_load_lds(
        (const __attribute__((address_space(1))) unsigned int*)g,
        (__attribute__((address_space(3))) unsigned int*)l, 16, 0, 0);
}
#endif

// --------------------------- format probe ----------------------------------
__global__ void probe_kernel(const unsigned short* x, int* flags) {
    __shared__ int mx[256];
    int m = 0;
    for (int i = threadIdx.x; i < 65536; i += 256) {
        int e = (x[i] >> 7) & 0xFF;
        m = m > e ? m : e;
    }
    mx[threadIdx.x] = m; __syncthreads();
    for (int s = 128; s > 0; s >>= 1) {
        if (threadIdx.x < s) mx[threadIdx.x] = mx[threadIdx.x] > mx[threadIdx.x + s] ? mx[threadIdx.x] : mx[threadIdx.x + s];
        __syncthreads();
    }
    if (threadIdx.x == 0) flags[0] = (mx[0] > 200) ? 1 : 0;
}
__global__ void report_ws_kernel(unsigned short* out, long long n, float code) {
    long long i = (long long)blockIdx.x * blockDim.x + threadIdx.x;
    const long long st = (long long)gridDim.x * blockDim.x;
    unsigned short c = f2bf(code);
    for (; i < n; i += st) out[i] = c;
}

// --------------------------- weight normalization --------------------------
// bf16 weight arena offsets (elements)
#define WF_OFF   0
#define WQW_OFF  196608
#define WOW_OFF  393216
#define WQG_OFF  458752
#define WOG_OFF  655360
#define M1W_OFF  720896
#define M2W_OFF  983040
#define WTOT     1245184
// f32 bias/gain/dwconv-weight arena offsets (elements)
#define BF_OFF   0
#define GW_OFF   256
#define BW_OFF   512
#define BQW_OFF  768
#define BOW_OFF  1536
#define GG_OFF   1792
#define BG_OFF   2048
#define BQG_OFF  2304
#define BOG_OFF  3072
#define GM_OFF   3328
#define BM_OFF   3584
#define M1B_OFF  3840
#define M2B_OFF  4864
#define DW1_OFF  5120
#define DW2_OFF  7424
#define DW3_OFF  13824
#define DB1_OFF  26368
#define DB2_OFF  26624
#define DB3_OFF  26880
#define BTOT     27136

template<int FMT>
__global__ __launch_bounds__(256) void convert_weights_kernel(
    const void* __restrict__ wf, const void* __restrict__ wqkv_w, const void* __restrict__ wo_w,
    const void* __restrict__ wqkv_g, const void* __restrict__ wo_g,
    const void* __restrict__ m1w, const void* __restrict__ m2w,
    unsigned short* __restrict__ out, const int* __restrict__ flags)
{
    if (flags[0] != FMT) return;
    int i = blockIdx.x * 256 + threadIdx.x;
    const int st = gridDim.x * 256;
    for (; i < WTOT; i += st) {
        const void* src; int off;
        if (i < WQW_OFF)      { src = wf;     off = i; }
        else if (i < WOW_OFF) { src = wqkv_w; off = i - WQW_OFF; }
        else if (i < WQG_OFF) { src = wo_w;   off = i - WOW_OFF; }
        else if (i < WOG_OFF) { src = wqkv_g; off = i - WQG_OFF; }
        else if (i < M1W_OFF) { src = wo_g;   off = i - WOG_OFF; }
        else if (i < M2W_OFF) { src = m1w;    off = i - M1W_OFF; }
        else                  { src = m2w;    off = i - M2W_OFF; }
        out[i] = (FMT == 0) ? ((const unsigned short*)src)[off]
                            : f2bf(((const float*)src)[off]);
    }
}

template<int FMT>
__global__ __launch_bounds__(256) void convert_bias_kernel(
    const void* bf_, const void* gw, const void* bw, const void* bqkv_w, const void* bo_w,
    const void* gg, const void* bg, const void* bqkv_g, const void* bo_g,
    const void* gm, const void* bm, const void* m1b, const void* m2b,
    const void* w1, const void* w2, const void* w3,
    const void* b1, const void* b2, const void* b3,
    float* __restrict__ out, const int* __restrict__ flags)
{
    if (flags[0] != FMT) return;
    int i = blockIdx.x * 256 + threadIdx.x;
    const int st = gridDim.x * 256;
    for (; i < BTOT; i += st) {
        const void* src; int off;
        if (i < GW_OFF)        { src = bf_;    off = i; }
        else if (i < BW_OFF)   { src = gw;     off = i - GW_OFF; }
        else if (i < BQW_OFF)  { src = bw;     off = i - BW_OFF; }
        else if (i < BOW_OFF)  { src = bqkv_w; off = i - BQW_OFF; }
        else if (i < GG_OFF)   { src = bo_w;   off = i - BOW_OFF; }
        else if (i < BG_OFF)   { src = gg;     off = i - GG_OFF; }
        else if (i < BQG_OFF)  { src = bg;     off = i - BG_OFF; }
        else if (i < BOG_OFF)  { src = bqkv_g; off = i - BQG_OFF; }
        else if (i < GM_OFF)   { src = bo_g;   off = i - BOG_OFF; }
        else if (i < BM_OFF)   { src = gm;     off = i - GM_OFF; }
        else if (i < M1B_OFF)  { src = bm;     off = i - BM_OFF; }
        else if (i < M2B_OFF)  { src = m1b;    off = i - M1B_OFF; }
        else if (i < DW1_OFF)  { src = m2b;    off = i - M2B_OFF; }
        else if (i < DW2_OFF)  { src = w1;     off = i - DW1_OFF; }
        else if (i < DW3_OFF)  { src = w2;     off = i - DW2_OFF; }
        else if (i < DB1_OFF)  { src = w3;     off = i - DW3_OFF; }
        else if (i < DB2_OFF)  { src = b1;     off = i - DB1_OFF; }
        else if (i < DB3_OFF)  { src = b2;     off = i - DB2_OFF; }
        else                   { src = b3;     off = i - DB3_OFF; }
        out[i] = ldin<FMT>(src, off);
    }
}

// --------------------------- pipeline kernels ------------------------------
// transpose_in: [B,C,HW] -> [B,HW,C] f32. Vectorized 4-wide global reads.
template<int FMT>
__global__ __launch_bounds__(256) void transpose_in_kernel(
    const void* __restrict__ in, float* __restrict__ out, const int* __restrict__ flags)
{
    if (flags[0] != FMT) return;
    __shared__ float tile[64][65];
    const int b  = blockIdx.z;
    const int s0 = blockIdx.x * 64;    // hw base
    const int r0 = blockIdx.y * 64;    // channel base
    const int tx = threadIdx.x & 63;
    const int ty = threadIdx.x >> 6;
    const size_t sb = (size_t)b * CC * HWSZ;
    float* dst = out + (size_t)b * HWSZ * CC;

    // read: each thread loads 4 consecutive hw for one channel row
    const int hw4 = (threadIdx.x & 15) * 4;
    const int chb = threadIdx.x >> 4;   // 0..15
#pragma unroll
    for (int p = 0; p < 4; ++p) {
        const int ch = chb + p * 16;
        const size_t gi = sb + (size_t)(r0 + ch) * HWSZ + s0 + hw4;
        float v0, v1, v2, v3;
        if (FMT == 0) {
            ushort4 u = *(const ushort4*)((const unsigned short*)in + gi);
            v0 = bf2f(u.x); v1 = bf2f(u.y); v2 = bf2f(u.z); v3 = bf2f(u.w);
        } else {
            float4 f = *(const float4*)((const float*)in + gi);
            v0 = f.x; v1 = f.y; v2 = f.z; v3 = f.w;
        }
        tile[ch][hw4] = v0; tile[ch][hw4 + 1] = v1;
        tile[ch][hw4 + 2] = v2; tile[ch][hw4 + 3] = v3;
    }
    __syncthreads();
    // write: [hw][ch] f32, lanes over ch (coalesced)
#pragma unroll
    for (int rr = 0; rr < 16; ++rr) {
        int srow = ty + rr * 4;   // hw within tile
        dst[(size_t)(s0 + srow) * CC + r0 + tx] = tile[tx][srow];
    }
}

// transpose_out: [B,HW,C] f32 -> [B,C,HW] out. Vectorized 4-wide global writes.
template<int FMT>
__global__ __launch_bounds__(256) void transpose_out_kernel(
    const float* __restrict__ in, void* __restrict__ out, const int* __restrict__ flags)
{
    if (flags[0] != FMT) return;
    __shared__ float tile[64][65];
    const int b  = blockIdx.z;
    const int h0 = blockIdx.x * 64;    // hw base
    const int c0 = blockIdx.y * 64;    // channel base
    const float* src = in + (size_t)b * HWSZ * CC;
    const size_t db = (size_t)b * CC * HWSZ;

    // read: [hw][ch] f32, thread loads float4 of channels
    const int ch4 = (threadIdx.x & 15) * 4;
    const int hwb = threadIdx.x >> 4;   // 0..15
#pragma unroll
    for (int p = 0; p < 4; ++p) {
        const int hw = hwb + p * 16;
        float4 f = *(const float4*)(src + (size_t)(h0 + hw) * CC + c0 + ch4);
        tile[hw][ch4] = f.x; tile[hw][ch4 + 1] = f.y;
        tile[hw][ch4 + 2] = f.z; tile[hw][ch4 + 3] = f.w;
    }
    __syncthreads();
    // write: [ch][hw], thread writes 4 consecutive hw
    const int hw4 = (threadIdx.x & 15) * 4;
    const int chb = threadIdx.x >> 4;
#pragma unroll
    for (int p = 0; p < 4; ++p) {
        const int ch = chb + p * 16;
        const size_t di = db + (size_t)(c0 + ch) * HWSZ + h0 + hw4;
        float v0 = tile[hw4][ch], v1 = tile[hw4 + 1][ch];
        float v2 = tile[hw4 + 2][ch], v3 = tile[hw4 + 3][ch];
        if (FMT) {
            float4 f; f.x = v0; f.y = v1; f.z = v2; f.w = v3;
            *(float4*)((float*)out + di) = f;
        } else {
            ushort4 u;
            u.x = f2bf(v0); u.y = f2bf(v1); u.z = f2bf(v2); u.w = f2bf(v3);
            *(ushort4*)((unsigned short*)out + di) = u;
        }
    }
}

// dwconv: 8 output rows x 128 cols per block; each thread 4 cols of one row.
// Register sliding window: 3 aligned float4 LDS reads per input row.
// Weights/biases from f32 arena (block-uniform -> scalar loads).
template<int FMT>
__global__ __launch_bounds__(256) void dwconv_cat_kernel(
    const void* __restrict__ x, const float* __restrict__ arena,
    unsigned short* __restrict__ cat, int Mc, const int* __restrict__ flags)
{
    if (flags[0] != FMT) return;
    __shared__ float patch[14][140];   // rows h0-3..h0+10; col = gw+4 (cols 1..134 used)
    const int hb = blockIdx.x;
    const int c  = blockIdx.y;
    const int b  = blockIdx.z;
    const int tid = threadIdx.x;

    const int h0 = hb * 8;
    const size_t xb = ((size_t)b * CC + c) * HWSZ;

    // interior: 14 rows x 32 chunks of 4 (gw = c4..c4+3 -> patch col gw+4)
    for (int i = tid; i < 448; i += 256) {
        const int r  = i >> 5;
        const int c4 = (i & 31) * 4;
        const int gh = h0 - 3 + r;
        float4 vv;
        if (gh >= 0 && gh < HH) {
            if (FMT == 0) {
                ushort4 u = *(const ushort4*)((const unsigned short*)x + xb + (size_t)gh * WW + c4);
                vv.x = bf2f(u.x); vv.y = bf2f(u.y); vv.z = bf2f(u.z); vv.w = bf2f(u.w);
            } else {
                vv = *(const float4*)((const float*)x + xb + (size_t)gh * WW + c4);
            }
        } else { vv.x = vv.y = vv.z = vv.w = 0.f; }
        *(float4*)&patch[r][c4 + 4] = vv;
    }
    // halo: 14 rows x 6 cols (gw -3..-1 -> cols 1..3, gw 128..130 -> cols 132..134)
    for (int i = tid; i < 84; i += 256) {
        const int r = i / 6, j = i % 6;
        const int gh = h0 - 3 + r;
        const int gw = (j < 3) ? (j - 3) : (125 + j);
        float v = 0.f;
        if (gh >= 0 && gh < HH && gw >= 0 && gw < WW)
            v = ldin<FMT>(x, xb + (size_t)gh * WW + gw);
        patch[r][gw + 4] = v;
    }
    __syncthreads();

    const int rowIdx = tid >> 5;         // 0..7 output row
    const int cb     = (tid & 31) * 4;   // output col base

    const float* wt1 = arena + DW1_OFF + c * 9;
    const float* wt2 = arena + DW2_OFF + c * 25;
    const float* wt3 = arena + DW3_OFF + c * 49;
    const float bb1 = arena[DB1_OFF + c];
    const float bb2 = arena[DB2_OFF + c];
    const float bb3 = arena[DB3_OFF + c];

    float s1[4] = {bb1, bb1, bb1, bb1};
    float s2[4] = {bb2, bb2, bb2, bb2};
    float s3[4] = {bb3, bb3, bb3, bb3};

#pragma unroll
    for (int r7 = 0; r7 < 7; ++r7) {
        const int prow = rowIdx + r7;             // patch row = (row+3) + (r7-3)
        float4 a = *(const float4*)&patch[prow][cb];
        float4 d = *(const float4*)&patch[prow][cb + 4];
        float4 e = *(const float4*)&patch[prow][cb + 8];
        float vals[12] = {a.x, a.y, a.z, a.w, d.x, d.y, d.z, d.w, e.x, e.y, e.z, e.w};
        // s3: dx = dx7-3 -> vals[wi + dx7 + 1]
#pragma unroll
        for (int dx7 = 0; dx7 < 7; ++dx7) {
            const float wv = wt3[r7 * 7 + dx7];
#pragma unroll
            for (int wi = 0; wi < 4; ++wi) s3[wi] += vals[wi + dx7 + 1] * wv;
        }
        if (r7 >= 1 && r7 <= 5) {
#pragma unroll
            for (int dx5 = 0; dx5 < 5; ++dx5) {
                const float wv = wt2[(r7 - 1) * 5 + dx5];
#pragma unroll
                for (int wi = 0; wi < 4; ++wi) s2[wi] += vals[wi + dx5 + 2] * wv;
            }
        }
        if (r7 >= 2 && r7 <= 4) {
#pragma unroll
            for (int dx3 = 0; dx3 < 3; ++dx3) {
                const float wv = wt1[(r7 - 2) * 3 + dx3];
#pragma unroll
                for (int wi = 0; wi < 4; ++wi) s1[wi] += vals[wi + dx3 + 3] * wv;
            }
        }
    }

    const size_t m = (size_t)b * HWSZ + (size_t)(h0 + rowIdx) * WW + cb;
    ushort4 o1, o2, o3;
    o1.x = f2bf(s1[0]); o1.y = f2bf(s1[1]); o1.z = f2bf(s1[2]); o1.w = f2bf(s1[3]);
    o2.x = f2bf(s2[0]); o2.y = f2bf(s2[1]); o2.z = f2bf(s2[2]); o2.w = f2bf(s2[3]);
    o3.x = f2bf(s3[0]); o3.y = f2bf(s3[1]); o3.z = f2bf(s3[2]); o3.w = f2bf(s3[3]);
    *(ushort4*)&cat[(size_t)c * Mc + m]         = o1;
    *(ushort4*)&cat[(size_t)(256 + c) * Mc + m] = o2;
    *(ushort4*)&cat[(size_t)(512 + c) * Mc + m] = o3;
}

// ---------------------------------------------------------------------------
// MFMA GEMM (unchanged): C[M,N] = A*W^T + bias, W bf16 [N][K].
// ---------------------------------------------------------------------------
template<int ALAYOUT, int EPI>
__global__ __launch_bounds__(256) void gemm_mfma_kernel(
    const unsigned short* __restrict__ A, const unsigned short* __restrict__ Bw,
    const float* __restrict__ bias, void* __restrict__ Cout,
    int N, int K, int lda)
{
    constexpr int ASTR = ALAYOUT ? 72 : 64;
    __shared__ unsigned short As[128 * ASTR];
    __shared__ unsigned short Bs[128 * 64];
    const int tid  = threadIdx.x;
    const int lane = tid & 63;
    const int wv   = tid >> 6;
    const int wm   = (wv >> 1) * 64;
    const int wn   = (wv & 1) * 64;
    const int l15  = lane & 15;
    const int quad = lane >> 4;

    const int nbx = gridDim.x;
    const int nwg = nbx * gridDim.y;
    const int bid = blockIdx.y * nbx + blockIdx.x;
    const int swz = (bid & 7) * (nwg >> 3) + (bid >> 3);
    const int m0 = (swz / nbx) * 128;
    const int n0 = (swz % nbx) * 128;

    const int sr   = lane >> 3;
    const int scol = (lane & 7) * 8;

    float4v acc[4][4] = {};

    for (int k0 = 0; k0 < K; k0 += 64) {
        __syncthreads();
        if (ALAYOUT == 0) {
            const unsigned short* ga = A + (size_t)(m0 + wv * 32 + sr) * K + k0 + scol;
#pragma unroll
            for (int p = 0; p < 4; ++p) {
                unsigned short* lb = &As[(wv * 32 + p * 8) * 64];
#if USE_GLDS
                gload16(ga + (size_t)(p * 8) * K, lb);
#else
                *(short8v*)(lb + lane * 8) = *(const short8v*)(ga + (size_t)(p * 8) * K);
#endif
            }
        } else {
#pragma unroll
            for (int p = 0; p < 4; ++p) {
                const int k  = p * 16 + (tid >> 4);
                const int mm = (tid & 15) * 8;
                const unsigned short* g = A + (size_t)(k0 + k) * lda + m0 + mm;
                ushort4 va = *(const ushort4*)g;
                ushort4 vb = *(const ushort4*)(g + 4);
                As[(mm + 0) * 72 + k] = va.x; As[(mm + 1) * 72 + k] = va.y;
                As[(mm + 2) * 72 + k] = va.z; As[(mm + 3) * 72 + k] = va.w;
                As[(mm + 4) * 72 + k] = vb.x; As[(mm + 5) * 72 + k] = vb.y;
                As[(mm + 6) * 72 + k] = vb.z; As[(mm + 7) * 72 + k] = vb.w;
            }
        }
        {
            const unsigned short* gb = Bw + (size_t)(n0 + wv * 32 + sr) * K + k0 + scol;
#pragma unroll
            for (int p = 0; p < 4; ++p) {
                unsigned short* lb = &Bs[(wv * 32 + p * 8) * 64];
#if USE_GLDS
                gload16(gb + (size_t)(p * 8) * K, lb);
#else
                *(short8v*)(lb + lane * 8) = *(const short8v*)(gb + (size_t)(p * 8) * K);
#endif
            }
        }
#if USE_GLDS
        asm volatile("s_waitcnt vmcnt(0)" ::: "memory");
#endif
        __syncthreads();

#pragma unroll
        for (int ks = 0; ks < 64; ks += 32) {
            short8v af[4], bfv[4];
#pragma unroll
            for (int i = 0; i < 4; ++i)
                af[i] = *(const short8v*)&As[(wm + i * 16 + l15) * ASTR + ks + quad * 8];
#pragma unroll
            for (int i = 0; i < 4; ++i)
                bfv[i] = *(const short8v*)&Bs[(wn + i * 16 + l15) * 64 + ks + quad * 8];
#pragma unroll
            for (int mi = 0; mi < 4; ++mi)
#pragma unroll
                for (int ni = 0; ni < 4; ++ni)
                    acc[mi][ni] = __builtin_amdgcn_mfma_f32_16x16x32_bf16(
                        af[mi], bfv[ni], acc[mi][ni], 0, 0, 0);
        }
    }

    float bv[4];
#pragma unroll
    for (int ni = 0; ni < 4; ++ni) bv[ni] = bias[n0 + wn + ni * 16 + l15];

#pragma unroll
    for (int mi = 0; mi < 4; ++mi) {
#pragma unroll
        for (int r = 0; r < 4; ++r) {
            const size_t row = (size_t)(m0 + wm + mi * 16 + quad * 4 + r);
#pragma unroll
            for (int ni = 0; ni < 4; ++ni) {
                const int col = n0 + wn + ni * 16 + l15;
                float v = acc[mi][ni][r] + bv[ni];
                if (EPI == 0) {
                    ((unsigned short*)Cout)[row * N + col] = f2bf(v);
                } else if (EPI == 1) {
                    float g = 0.5f * v * (1.0f + erff(v * 0.70710678118654752f));
                    ((unsigned short*)Cout)[row * N + col] = f2bf(g);
                } else {
                    ((float*)Cout)[row * N + col] += v;
                }
            }
        }
    }
}

// LayerNorm over C=256.
template<int FIN>
__global__ __launch_bounds__(256) void ln_kernel(
    const void* __restrict__ inv, const float* __restrict__ g,
    const float* __restrict__ b, unsigned short* __restrict__ out)
{
    const int lane = threadIdx.x & 63;
    const int wv   = threadIdx.x >> 6;
    const size_t m = (size_t)blockIdx.x * 4 + wv;
    const int c0 = lane * 4;
    float v[4];
    if (FIN == 0) {
        ushort4 u = *(const ushort4*)((const unsigned short*)inv + m * CC + c0);
        v[0] = bf2f(u.x); v[1] = bf2f(u.y); v[2] = bf2f(u.z); v[3] = bf2f(u.w);
    } else {
        float4 f = *(const float4*)((const float*)inv + m * CC + c0);
        v[0] = f.x; v[1] = f.y; v[2] = f.z; v[3] = f.w;
    }
    float s  = v[0] + v[1] + v[2] + v[3];
    float sq = v[0]*v[0] + v[1]*v[1] + v[2]*v[2] + v[3]*v[3];
#pragma unroll
    for (int off = 32; off > 0; off >>= 1) {
        s  += __shfl_xor(s,  off);
        sq += __shfl_xor(sq, off);
    }
    const float mean = s * 0.00390625f;
    float var = sq * 0.00390625f - mean * mean;
    if (var < 0.f) var = 0.f;
    const float rs = rsqrtf(var + 1e-5f);
    ushort4 o;
    o.x = f2bf((v[0] - mean) * rs * g[c0 + 0] + b[c0 + 0]);
    o.y = f2bf((v[1] - mean) * rs * g[c0 + 1] + b[c0 + 1]);
    o.z = f2bf((v[2] - mean) * rs * g[c0 + 2] + b[c0 + 2]);
    o.w = f2bf((v[3] - mean) * rs * g[c0 + 3] + b[c0 + 3]);
    *(ushort4*)(out + m * CC + c0) = o;
}

// ---------------------------------------------------------------------------
// MFMA windowed attention (unchanged from round 6).
// ---------------------------------------------------------------------------
template<int MODE>
__global__ __launch_bounds__(256) void attn_kernel(
    const unsigned short* __restrict__ qkv, unsigned short* __restrict__ attn_out)
{
    __shared__ unsigned short q_lds[64 * 72];
    __shared__ unsigned short k_lds[64 * 72];
    __shared__ unsigned short v_lds[64 * 72];
    __shared__ unsigned short vt_lds[32 * 72];
    __shared__ unsigned short p_lds[64 * 72];

    const int tid  = threadIdx.x;
    const int lane = tid & 63;
    const int wv   = tid >> 6;
    const int l15  = lane & 15;
    const int quad = lane >> 4;
    const int wi   = blockIdx.x;
    const int b    = wi >> 8;
    const int rem  = wi & 255;
    const int i2   = rem >> 4;
    const int j2   = rem & 15;

    const float scale = 0.17677669529663687f;

    auto gt_read = [&](int tok) -> size_t {
        const int p = tok >> 3, qq = tok & 7;
        int h_r, w_r;
        if (MODE == 0) { h_r = i2 * 8 + p;  w_r = j2 * 8 + qq; }
        else           { h_r = p * 16 + i2; w_r = qq * 16 + j2; }
        return (size_t)b * HWSZ + (size_t)h_r * WW + w_r;
    };
    auto gt_write = [&](int tok) -> size_t {
        const int p = tok >> 3, qq = tok & 7;
        int h_w, w_w;
        if (MODE == 0) { h_w = i2 * 8 + p; w_w = j2 * 8 + qq; }
        else { h_w = j2 * 8 + (i2 >> 1); w_w = (i2 & 1) * 64 + p * 8 + qq; }
        return (size_t)b * HWSZ + (size_t)h_w * WW + w_w;
    };

    for (int g = 0; g < 4; ++g) {
        for (int v = tid; v < 512; v += 256) {
            const int tok = v >> 3;
            const int cg  = (v & 7) * 8;
            const unsigned short* src = qkv + gt_read(tok) * 768 + g * 64 + cg;
            *(short8v*)&q_lds[tok * 72 + cg] = *(const short8v*)(src);
            *(short8v*)&k_lds[tok * 72 + cg] = *(const short8v*)(src + 256);
            *(short8v*)&v_lds[tok * 72 + cg] = *(const short8v*)(src + 512);
        }
        __syncthreads();

#pragma unroll
        for (int hl = 0; hl < 2; ++hl) {
            {
                const int tok = lane;
                const int dg  = wv * 8;
                short8v vv = *(const short8v*)&v_lds[tok * 72 + hl * 32 + dg];
#pragma unroll
                for (int j = 0; j < 8; ++j)
                    vt_lds[(dg + j) * 72 + tok] = (unsigned short)vv[j];
            }

            short8v af = *(const short8v*)&q_lds[(16 * wv + l15) * 72 + hl * 32 + quad * 8];
            float4v s[4];
#pragma unroll
            for (int ni = 0; ni < 4; ++ni) {
                short8v bfv = *(const short8v*)&k_lds[(16 * ni + l15) * 72 + hl * 32 + quad * 8];
                float4v z = {};
                s[ni] = __builtin_amdgcn_mfma_f32_16x16x32_bf16(af, bfv, z, 0, 0, 0);
            }

#pragma unroll
            for (int r = 0; r < 4; ++r) {
                float m1 = fmaxf(fmaxf(s[0][r], s[1][r]), fmaxf(s[2][r], s[3][r]));
#pragma unroll
                for (int off = 1; off < 16; off <<= 1) m1 = fmaxf(m1, __shfl_xor(m1, off));
                const float rowmax = m1 * scale;
                float sum = 0.f;
#pragma unroll
                for (int ni = 0; ni < 4; ++ni) {
                    const float e = __expf(s[ni][r] * scale - rowmax);
                    s[ni][r] = e; sum += e;
                }
#pragma unroll
                for (int off = 1; off < 16; off <<= 1) sum += __shfl_xor(sum, off);
                const float inv = 1.f / sum;
#pragma unroll
                for (int ni = 0; ni < 4; ++ni) s[ni][r] *= inv;
            }

#pragma unroll
            for (int ni = 0; ni < 4; ++ni)
#pragma unroll
                for (int r = 0; r < 4; ++r)
                    p_lds[(16 * wv + quad * 4 + r) * 72 + ni * 16 + l15] = f2bf(s[ni][r]);

            __syncthreads();

            float4v o[2] = {};
#pragma unroll
            for (int kk = 0; kk < 2; ++kk) {
                short8v pf = *(const short8v*)&p_lds[(16 * wv + l15) * 72 + kk * 32 + quad * 8];
#pragma unroll
                for (int dt = 0; dt < 2; ++dt) {
                    short8v vf = *(const short8v*)&vt_lds[(dt * 16 + l15) * 72 + kk * 32 + quad * 8];
                    o[dt] = __builtin_amdgcn_mfma_f32_16x16x32_bf16(pf, vf, o[dt], 0, 0, 0);
                }
            }

            const int head = g * 2 + hl;
#pragma unroll
            for (int r = 0; r < 4; ++r) {
                const int tok = 16 * wv + quad * 4 + r;
                unsigned short* op = attn_out + gt_write(tok) * CC + head * 32;
                op[l15]      = f2bf(o[0][r]);
                op[16 + l15] = f2bf(o[1][r]);
            }
            __syncthreads();
        }
    }
}

// ---------------------------------------------------------------------------
extern "C" void kernel_launch(void* const* d_in, const int* in_sizes, int n_in,
                              void* d_out, int out_size, void* d_ws, size_t ws_size,
                              hipStream_t stream)
{
    const void* x      = d_in[0];
    const void* w1     = d_in[1];  const void* b1  = d_in[2];
    const void* w2     = d_in[3];  const void* b2  = d_in[4];
    const void* w3     = d_in[5];  const void* b3  = d_in[6];
    const void* wf     = d_in[7];  const void* bf_ = d_in[8];
    const void* gw     = d_in[9];  const void* bw  = d_in[10];
    const void* wqkv_w = d_in[11]; const void* bqkv_w = d_in[12];
    const void* wo_w   = d_in[13]; const void* bo_w   = d_in[14];
    const void* gg     = d_in[15]; const void* bg  = d_in[16];
    const void* wqkv_g = d_in[17]; const void* bqkv_g = d_in[18];
    const void* wo_g   = d_in[19]; const void* bo_g   = d_in[20];
    const void* gm     = d_in[21]; const void* bm  = d_in[22];
    const void* m1w    = d_in[23]; const void* m1b = d_in[24];
    const void* m2w    = d_in[25]; const void* m2b = d_in[26];

    const size_t MiB = 1048576ull;
    const long long nout = (long long)out_size;

    if (72 * MiB > ws_size) {
        float wsMiB = (float)(ws_size / MiB);
        if (wsMiB > 8192.f) wsMiB = 8192.f;
        report_ws_kernel<<<1024, 256, 0, stream>>>((unsigned short*)d_out, nout, 1024.f + wsMiB);
        return;
    }

    int nb = 8;
    while (nb > 1 && (size_t)nb * 64 * MiB + 8 * MiB > ws_size) nb >>= 1;
    const int nchunks = 8 / nb;
    const int Mc = nb * HWSZ;

    char* ws = (char*)d_ws;
    float*          xs   = (float*)ws;
    unsigned short* regA = (unsigned short*)(ws + (size_t)nb * 16 * MiB);
    unsigned short* xmat = (unsigned short*)(ws + (size_t)nb * 48 * MiB);
    unsigned short* xln  = (unsigned short*)(ws + (size_t)nb * 56 * MiB);
    int*            flags = (int*)(ws + (size_t)nb * 64 * MiB);
    unsigned short* wbf  = (unsigned short*)(ws + (size_t)nb * 64 * MiB + 1 * MiB);
    float*          bcv  = (float*)(ws + (size_t)nb * 64 * MiB + 4 * MiB);

    probe_kernel<<<1, 256, 0, stream>>>((const unsigned short*)x, flags);
    convert_weights_kernel<0><<<1024, 256, 0, stream>>>(wf, wqkv_w, wo_w, wqkv_g, wo_g, m1w, m2w, wbf, flags);
    convert_weights_kernel<1><<<1024, 256, 0, stream>>>(wf, wqkv_w, wo_w, wqkv_g, wo_g, m1w, m2w, wbf, flags);
    convert_bias_kernel<0><<<106, 256, 0, stream>>>(bf_, gw, bw, bqkv_w, bo_w, gg, bg, bqkv_g, bo_g, gm, bm, m1b, m2b, w1, w2, w3, b1, b2, b3, bcv, flags);
    convert_bias_kernel<1><<<106, 256, 0, stream>>>(bf_, gw, bw, bqkv_w, bo_w, gg, bg, bqkv_g, bo_g, gm, bm, m1b, m2b, w1, w2, w3, b1, b2, b3, bcv, flags);

    const int MB = Mc / 128;
    for (int c = 0; c < nchunks; ++c) {
        const size_t elemOff = (size_t)c * nb * CC * HWSZ;
        const void* xc0 = (const void*)((const unsigned short*)x + elemOff);
        const void* xc1 = (const void*)((const float*)x + elemOff);
        void* outc0 = (void*)((unsigned short*)d_out + elemOff);
        void* outc1 = (void*)((float*)d_out + elemOff);
        unsigned short* cat  = regA;
        unsigned short* qkvb = regA;
        unsigned short* h1   = regA;
        unsigned short* xm   = xmat;
        unsigned short* attn = xmat;

        transpose_in_kernel<0><<<dim3(256, 4, nb), 256, 0, stream>>>(xc0, xs, flags);
        transpose_in_kernel<1><<<dim3(256, 4, nb), 256, 0, stream>>>(xc1, xs, flags);

        dwconv_cat_kernel<0><<<dim3(16, 256, nb), 256, 0, stream>>>(xc0, bcv, cat, Mc, flags);
        dwconv_cat_kernel<1><<<dim3(16, 256, nb), 256, 0, stream>>>(xc1, bcv, cat, Mc, flags);

        gemm_mfma_kernel<1, 0><<<dim3(2, MB), 256, 0, stream>>>(cat, wbf + WF_OFF, bcv + BF_OFF, xm, 256, 768, Mc);

        // window branch
        ln_kernel<0><<<Mc / 4, 256, 0, stream>>>(xm, bcv + GW_OFF, bcv + BW_OFF, xln);
        gemm_mfma_kernel<0, 0><<<dim3(6, MB), 256, 0, stream>>>(xln, wbf + WQW_OFF, bcv + BQW_OFF, qkvb, 768, 256, 0);
        attn_kernel<0><<<nb * 256, 256, 0, stream>>>(qkvb, attn);
        gemm_mfma_kernel<0, 2><<<dim3(2, MB), 256, 0, stream>>>(attn, wbf + WOW_OFF, bcv + BOW_OFF, xs, 256, 256, 0);

        // grid branch
        ln_kernel<1><<<Mc / 4, 256, 0, stream>>>(xs, bcv + GG_OFF, bcv + BG_OFF, xln);
        gemm_mfma_kernel<0, 0><<<dim3(6, MB), 256, 0, stream>>>(xln, wbf + WQG_OFF, bcv + BQG_OFF, qkvb, 768, 256, 0);
        attn_kernel<1><<<nb * 256, 256, 0, stream>>>(qkvb, attn);
        gemm_mfma_kernel<0, 2><<<dim3(2, MB), 256, 0, stream>>>(attn, wbf + WOG_OFF, bcv + BOG_OFF, xs, 256, 256, 0);

        // MLP
        ln_kernel<1><<<Mc / 4, 256, 0, stream>>>(xs, bcv + GM_OFF, bcv + BM_OFF, xln);
        gemm_mfma_kernel<0, 1><<<dim3(8, MB), 256, 0, stream>>>(xln, wbf + M1W_OFF, bcv + M1B_OFF, h1, 1024, 256, 0);
        gemm_mfma_kernel<0, 2><<<dim3(2, MB), 256, 0, stream>>>(h1, wbf + M2W_OFF, bcv + M2B_OFF, xs, 256, 1024, 0);

        transpose_out_kernel<0><<<dim3(256, 4, nb), 256, 0, stream>>>(xs, outc0, flags);
        transpose_out_kernel<1><<<dim3(256, 4, nb), 256, 0, stream>>>(xs, outc1, flags);
    }
}